// Round 5
// baseline (728.969 us; speedup 1.0000x reference)
//
#include <hip/hip_runtime.h>
#include <math.h>

#define NT 16
#define NR 25
#define DZ 512
#define D2Z 1024
#define NC 64
#define NBLK 320

typedef short bf16x8 __attribute__((ext_vector_type(8)));
typedef float f32x4  __attribute__((ext_vector_type(4)));

#define TP  76   // convW LDS tile pitch (ushorts)
#define XP  72   // gemm xs pitch (ushorts) -> 144B rows, 16B aligned frags
#define WSP 72   // gemm ws pitch

static __device__ inline unsigned short f2bf(float v) {
    union { float f; unsigned u; } x; x.f = v;
    unsigned r = x.u + 0x7fffu + ((x.u >> 16) & 1u);
    return (unsigned short)(r >> 16);
}
static __device__ inline float bf2f(unsigned short h) {
    union { float f; unsigned u; } x; x.u = ((unsigned)h) << 16; return x.f;
}

struct SmemGemm {
    unsigned short xs_h[32 * XP], xs_l[32 * XP];
    unsigned short ws_h[128 * WSP], ws_l[128 * WSP];
};
struct SmemConv { unsigned short th[64 * TP], tl[64 * TP]; };
struct SmemRed  { float red[4][64]; };
union  alignas(16) Smem { SmemGemm g; SmemConv c; SmemRed r; };

// ---------------------------------------------------------------------------
// Manual grid barrier: single-use counter per barrier (zeroed by memset before
// launch). Release fence + device-scope arrive; acquire spin; acquire fence
// for all threads. 320 blocks <= 256 CUs -> all co-resident by construction.
// ---------------------------------------------------------------------------
static __device__ inline void gbar(int* c)
{
    __syncthreads();
    if (threadIdx.x == 0) {
        __threadfence();   // release: make this block's writes visible
        __hip_atomic_fetch_add(c, 1, __ATOMIC_ACQ_REL, __HIP_MEMORY_SCOPE_AGENT);
        while (__hip_atomic_load(c, __ATOMIC_ACQUIRE, __HIP_MEMORY_SCOPE_AGENT) < NBLK)
            __builtin_amdgcn_s_sleep(2);
    }
    __syncthreads();
    __threadfence();       // acquire: invalidate stale L1/L2 before reads
}

// ---------------------------------------------------------------------------
// S0a: convW virtual block (bx 0..23, by 0..15) — identical to R3 k_convW
// ---------------------------------------------------------------------------
static __device__ void dev_convW(int bx, int by, SmemConv& sm,
                                 const float* __restrict__ W1,
                                 unsigned short* __restrict__ W1h,
                                 unsigned short* __restrict__ W1l, int tid)
{
    int r0 = bx * 64;
    int j0 = by * 64;
    int c  = r0 >> 9;
    int rb = r0 & 511;

    #pragma unroll
    for (int it = 0; it < 4; it++) {
        int rl = (tid >> 4) + it * 16;
        int jj = (tid & 15) * 4;
        float4 v = *(const float4*)(W1 + (size_t)(r0 + rl) * D2Z + j0 + jj);
        unsigned short h0 = f2bf(v.x), h1 = f2bf(v.y), h2 = f2bf(v.z), h3 = f2bf(v.w);
        sm.th[rl * TP + jj + 0] = h0; sm.tl[rl * TP + jj + 0] = f2bf(v.x - bf2f(h0));
        sm.th[rl * TP + jj + 1] = h1; sm.tl[rl * TP + jj + 1] = f2bf(v.y - bf2f(h1));
        sm.th[rl * TP + jj + 2] = h2; sm.tl[rl * TP + jj + 2] = f2bf(v.z - bf2f(h2));
        sm.th[rl * TP + jj + 3] = h3; sm.tl[rl * TP + jj + 3] = f2bf(v.w - bf2f(h3));
    }
    __syncthreads();

    #pragma unroll
    for (int it = 0; it < 4; it++) {
        int jl = (tid >> 4) + it * 16;
        int r4 = (tid & 15) * 4;
        ushort4 hv = make_ushort4(sm.th[(r4+0)*TP + jl], sm.th[(r4+1)*TP + jl],
                                  sm.th[(r4+2)*TP + jl], sm.th[(r4+3)*TP + jl]);
        ushort4 lv = make_ushort4(sm.tl[(r4+0)*TP + jl], sm.tl[(r4+1)*TP + jl],
                                  sm.tl[(r4+2)*TP + jl], sm.tl[(r4+3)*TP + jl]);
        size_t dst = ((size_t)c * D2Z + j0 + jl) * DZ + rb + r4;
        *(ushort4*)(W1h + dst) = hv;
        *(ushort4*)(W1l + dst) = lv;
    }
    __syncthreads();   // protect smem reuse by next virtual block
}

// ---------------------------------------------------------------------------
// S0b: convX virtual block (bid 0..99)
// ---------------------------------------------------------------------------
static __device__ void dev_convX(int bid, const float* __restrict__ x,
                                 unsigned short* __restrict__ xh,
                                 unsigned short* __restrict__ xl, int tid)
{
    size_t i8 = ((size_t)bid * 256 + tid) * 8;
    float4 a = *(const float4*)(x + i8);
    float4 b = *(const float4*)(x + i8 + 4);
    unsigned short h;
    ushort4 ha, hb, la, lb;
    h = f2bf(a.x); ha.x = h; la.x = f2bf(a.x - bf2f(h));
    h = f2bf(a.y); ha.y = h; la.y = f2bf(a.y - bf2f(h));
    h = f2bf(a.z); ha.z = h; la.z = f2bf(a.z - bf2f(h));
    h = f2bf(a.w); ha.w = h; la.w = f2bf(a.w - bf2f(h));
    h = f2bf(b.x); hb.x = h; lb.x = f2bf(b.x - bf2f(h));
    h = f2bf(b.y); hb.y = h; lb.y = f2bf(b.y - bf2f(h));
    h = f2bf(b.z); hb.z = h; lb.z = f2bf(b.z - bf2f(h));
    h = f2bf(b.w); hb.w = h; lb.w = f2bf(b.w - bf2f(h));
    *(ushort4*)(xh + i8)     = ha;  *(ushort4*)(xh + i8 + 4) = hb;
    *(ushort4*)(xl + i8)     = la;  *(ushort4*)(xl + i8 + 4) = lb;
}

// ---------------------------------------------------------------------------
// S0c: dist virtual block (k, a) — identical arithmetic to R3 k_dist
// ---------------------------------------------------------------------------
static __device__ void dev_dist(int k, int a, const float* __restrict__ x,
                                float* __restrict__ Dm, int tid)
{
    int lane = tid & 63;
    int w    = tid >> 6;
    const float* xk = x + (size_t)k * NR * DZ;

    const float4* xap = (const float4*)(xk + a * DZ);
    float4 a0 = xap[lane];
    float4 a1 = xap[lane + 64];

    float sa = a0.x*a0.x + a0.y*a0.y + a0.z*a0.z + a0.w*a0.w
             + a1.x*a1.x + a1.y*a1.y + a1.z*a1.z + a1.w*a1.w;
    #pragma unroll
    for (int off = 32; off; off >>= 1) sa += __shfl_xor(sa, off);
    float inva = 1.0f / sqrtf(sa);
    a0.x *= inva; a0.y *= inva; a0.z *= inva; a0.w *= inva;
    a1.x *= inva; a1.y *= inva; a1.z *= inva; a1.w *= inva;
    float sqa = a0.x*a0.x + a0.y*a0.y + a0.z*a0.z + a0.w*a0.w
              + a1.x*a1.x + a1.y*a1.y + a1.z*a1.z + a1.w*a1.w;
    #pragma unroll
    for (int off = 32; off; off >>= 1) sqa += __shfl_xor(sqa, off);

    for (int j = w; j < NR; j += 4) {
        const float4* xjp = (const float4*)(xk + j * DZ);
        float4 j0 = xjp[lane];
        float4 j1 = xjp[lane + 64];
        float sj = j0.x*j0.x + j0.y*j0.y + j0.z*j0.z + j0.w*j0.w
                 + j1.x*j1.x + j1.y*j1.y + j1.z*j1.z + j1.w*j1.w;
        #pragma unroll
        for (int off = 32; off; off >>= 1) sj += __shfl_xor(sj, off);
        float invj = 1.0f / sqrtf(sj);
        j0.x *= invj; j0.y *= invj; j0.z *= invj; j0.w *= invj;
        j1.x *= invj; j1.y *= invj; j1.z *= invj; j1.w *= invj;

        float sqj = j0.x*j0.x + j0.y*j0.y + j0.z*j0.z + j0.w*j0.w
                  + j1.x*j1.x + j1.y*j1.y + j1.z*j1.z + j1.w*j1.w;
        float dij = a0.x*j0.x + a0.y*j0.y + a0.z*j0.z + a0.w*j0.w
                  + a1.x*j1.x + a1.y*j1.y + a1.z*j1.z + a1.w*j1.w;
        #pragma unroll
        for (int off = 32; off; off >>= 1) {
            sqj += __shfl_xor(sqj, off);
            dij += __shfl_xor(dij, off);
        }
        float d2 = sqa + sqj - 2.0f * dij;
        float d  = sqrtf(fmaxf(d2, 0.0f));
        if (lane == 0) Dm[((size_t)k * NR + a) * NR + j] = d;
    }
}

// ---------------------------------------------------------------------------
// S1: split-bf16 MFMA gemm virtual block (bid 0..311) — identical to R3
// ---------------------------------------------------------------------------
static __device__ void dev_gemm1(int bid, SmemGemm& sm,
                                 const unsigned short* __restrict__ xh,
                                 const unsigned short* __restrict__ xl,
                                 const unsigned short* __restrict__ W1h,
                                 const unsigned short* __restrict__ W1l,
                                 float* __restrict__ A, int tid)
{
    int mt = bid / 24, nt = bid % 24;
    int m0 = mt * 32;
    int n0 = nt * 128;
    int c  = n0 >> 10;
    int j0 = n0 & 1023;

    int lane = tid & 63;
    int wv   = tid >> 6;
    int wm   = wv >> 1, wn = wv & 1;
    int q    = lane >> 4;
    int ln16 = lane & 15;

    f32x4 acc[4];
    #pragma unroll
    for (int t = 0; t < 4; t++) acc[t] = (f32x4){0.f, 0.f, 0.f, 0.f};

    int xrow = tid >> 3;
    int xkg  = (tid & 7) * 8;
    const uint4 zero4 = make_uint4(0u, 0u, 0u, 0u);

    for (int kk = 0; kk < 8; kk++) {
        int kbase = kk * 64;
        {
            int gm = m0 + xrow;
            uint4 vh = zero4, vl = zero4;
            if (gm < 400) {
                size_t off = (size_t)gm * DZ + kbase + xkg;
                vh = *(const uint4*)(xh + off);
                vl = *(const uint4*)(xl + off);
            }
            *(uint4*)&sm.xs_h[xrow * XP + xkg] = vh;
            *(uint4*)&sm.xs_l[xrow * XP + xkg] = vl;
        }
        #pragma unroll
        for (int it = 0; it < 4; it++) {
            int g  = tid + 256 * it;
            int nl = g >> 3;
            int kg = (g & 7) * 8;
            size_t off = ((size_t)c * D2Z + j0 + nl) * DZ + kbase + kg;
            *(uint4*)&sm.ws_h[nl * WSP + kg] = *(const uint4*)(W1h + off);
            *(uint4*)&sm.ws_l[nl * WSP + kg] = *(const uint4*)(W1l + off);
        }
        __syncthreads();

        #pragma unroll
        for (int ks = 0; ks < 2; ks++) {
            int ko = ks * 32 + q * 8;
            bf16x8 a_h = *(const bf16x8*)&sm.xs_h[(wm * 16 + ln16) * XP + ko];
            bf16x8 a_l = *(const bf16x8*)&sm.xs_l[(wm * 16 + ln16) * XP + ko];
            #pragma unroll
            for (int t = 0; t < 4; t++) {
                int nl = wn * 64 + t * 16 + ln16;
                bf16x8 b_h = *(const bf16x8*)&sm.ws_h[nl * WSP + ko];
                bf16x8 b_l = *(const bf16x8*)&sm.ws_l[nl * WSP + ko];
                acc[t] = __builtin_amdgcn_mfma_f32_16x16x32_bf16(a_h, b_h, acc[t], 0, 0, 0);
                acc[t] = __builtin_amdgcn_mfma_f32_16x16x32_bf16(a_h, b_l, acc[t], 0, 0, 0);
                acc[t] = __builtin_amdgcn_mfma_f32_16x16x32_bf16(a_l, b_h, acc[t], 0, 0, 0);
            }
        }
        __syncthreads();
    }

    #pragma unroll
    for (int t = 0; t < 4; t++) {
        int j = j0 + wn * 64 + t * 16 + ln16;
        #pragma unroll
        for (int r = 0; r < 4; r++) {
            int m = m0 + wm * 16 + q * 4 + r;
            if (m < 400) {
                int kT = m / 25, i = m % 25;
                A[(((size_t)kT * 3 + c) * NR + i) * D2Z + j] = acc[t][r];
            }
        }
    }
}

// ---------------------------------------------------------------------------
// S2: accum virtual block (jt, ag, k) — identical to R3 k_accum
// ---------------------------------------------------------------------------
static __device__ void dev_accum(int jt, int ag, int k,
                                 const float* __restrict__ A,
                                 const float* __restrict__ Dm,
                                 const float* __restrict__ b1,
                                 float* __restrict__ G,
                                 float* __restrict__ cnt, int tid)
{
    int j = jt * 256 + tid;

    const float* Ab = A + (size_t)k * 75 * D2Z + j;
    float a2v[25], a3v[25];
    #pragma unroll
    for (int i = 0; i < 25; i++) a2v[i] = Ab[(size_t)(25 + i) * D2Z];
    #pragma unroll
    for (int i = 0; i < 25; i++) a3v[i] = Ab[(size_t)(50 + i) * D2Z];
    float b1v = b1[j];

    float acc = 0.0f, cntv = 0.0f;
    for (int qa = 0; qa < 5; qa++) {
        int a = ag * 5 + qa;
        float a1 = Ab[(size_t)a * D2Z];
        const float* Dk = Dm + ((size_t)k * NR + a) * NR;
        #pragma unroll
        for (int m = 0; m < 5; m++) {
            if (m == ag) continue;
            int p = qa + 5 * m;
            float dap = Dk[p];
            float s = a1 + a2v[p] + b1v;
            #pragma unroll
            for (int n = 0; n < 25; n++) {
                if ((n % 5) == qa) continue;
                float tm = Dk[n] - dap;
                bool sel = (tm > 0.0f) && (tm <= 0.8f);
                float pre = fmaxf(s + a3v[n], 0.0f);
                float msk = sel ? 1.0f : 0.0f;
                acc = fmaf(msk, pre, acc);
                cntv += msk;
            }
        }
    }

    atomicAdd(&G[(size_t)k * D2Z + j], acc);
    if (jt == 0 && tid == 0) atomicAdd(&cnt[k], cntv);
}

// ---------------------------------------------------------------------------
// S3..S6: tail virtual blocks — identical arithmetic to R3
// ---------------------------------------------------------------------------
static __device__ void dev_pooled(int bx, int k, SmemRed& sm,
                                  const float* __restrict__ G,
                                  const float* __restrict__ cnt,
                                  const float* __restrict__ W2,
                                  const float* __restrict__ b2,
                                  float* __restrict__ pooled, int tid)
{
    int lane = tid & 63, kc = tid >> 6;
    int col = bx * 64 + lane;

    const float* Gk = G + (size_t)k * D2Z;
    float acc = 0.0f;
    int j0 = kc * 256;
    #pragma unroll 4
    for (int jj = j0; jj < j0 + 256; jj++)
        acc = fmaf(Gk[jj], W2[(size_t)jj * DZ + col], acc);

    sm.red[kc][lane] = acc;
    __syncthreads();
    if (tid < 64) {
        float s = sm.red[0][lane] + sm.red[1][lane] + sm.red[2][lane] + sm.red[3][lane];
        s += cnt[k] * b2[col];
        pooled[(size_t)k * DZ + col] = s;
    }
    __syncthreads();
}

static __device__ void dev_u(int bx, int k, SmemRed& sm,
                             const float* __restrict__ pooled,
                             const float* __restrict__ W3,
                             const float* __restrict__ b3,
                             float* __restrict__ u, int tid)
{
    int lane = tid & 63, kc = tid >> 6;
    int col = bx * 64 + lane;

    const float* Pk = pooled + (size_t)k * DZ;
    float acc = 0.0f;
    int s0 = kc * 128;
    #pragma unroll 4
    for (int s = s0; s < s0 + 128; s++)
        acc = fmaf(Pk[s], W3[(size_t)s * D2Z + col], acc);

    sm.red[kc][lane] = acc;
    __syncthreads();
    if (tid < 64) {
        float v = sm.red[0][lane] + sm.red[1][lane] + sm.red[2][lane] + sm.red[3][lane] + b3[col];
        u[(size_t)k * D2Z + col] = fmaxf(v, 0.0f);
    }
    __syncthreads();
}

static __device__ void dev_o(int bx, int k, SmemRed& sm,
                             const float* __restrict__ u,
                             const float* __restrict__ W4,
                             const float* __restrict__ b4,
                             float* __restrict__ o, int tid)
{
    int lane = tid & 63, kc = tid >> 6;
    int col = bx * 64 + lane;

    const float* Uk = u + (size_t)k * D2Z;
    float acc = 0.0f;
    int j0 = kc * 256;
    #pragma unroll 4
    for (int jj = j0; jj < j0 + 256; jj++)
        acc = fmaf(Uk[jj], W4[(size_t)jj * DZ + col], acc);

    sm.red[kc][lane] = acc;
    __syncthreads();
    if (tid < 64) {
        o[(size_t)k * DZ + col] = sm.red[0][lane] + sm.red[1][lane] + sm.red[2][lane]
                                + sm.red[3][lane] + b4[col];
    }
    __syncthreads();
}

static __device__ void dev_score(int k, SmemRed& sm,
                                 const float* __restrict__ o,
                                 const float* __restrict__ Wc,
                                 const float* __restrict__ bc,
                                 float* __restrict__ out, int tid)
{
    int oc = tid & 63, kc = tid >> 6;

    const float* Ok = o + (size_t)k * DZ;
    float acc = 0.0f;
    int r0 = kc * 128;
    #pragma unroll 4
    for (int rr = r0; rr < r0 + 128; rr++)
        acc = fmaf(Ok[rr], Wc[(size_t)rr * NC + oc], acc);

    sm.red[kc][oc] = acc;
    __syncthreads();
    if (tid < 64) {
        float sc = bc[tid] + sm.red[0][tid] + sm.red[1][tid] + sm.red[2][tid] + sm.red[3][tid];
        float m = sc;
        #pragma unroll
        for (int off = 32; off; off >>= 1) m = fmaxf(m, __shfl_xor(m, off));
        float e = expf(sc - m);
        float ss = e;
        #pragma unroll
        for (int off = 32; off; off >>= 1) ss += __shfl_xor(ss, off);
        out[k * NC + tid] = e / ss;
    }
    __syncthreads();
}

// ---------------------------------------------------------------------------
// Mega kernel, plain launch, manual global barriers. 320 blocks x 256.
// ---------------------------------------------------------------------------
__global__ __launch_bounds__(256, 2) void k_mega(
    const float* x,  const float* W1, const float* b1, const float* W2,
    const float* b2, const float* W3, const float* b3, const float* W4,
    const float* b4, const float* Wc, const float* bc, float* out,
    float* Dm, float* cnt, float* G, float* A,
    float* pooled, float* uu, float* oo,
    unsigned short* W1h, unsigned short* W1l,
    unsigned short* xh,  unsigned short* xl, int* bar)
{
    __shared__ Smem sm;
    int tid = threadIdx.x;
    int b0  = blockIdx.x;

    // ---- S0: convW (384) | convX (100) | dist (400) | zero G+cnt (65) ----
    for (int vb = b0; vb < 949; vb += NBLK) {
        if (vb < 384) {
            dev_convW(vb % 24, vb / 24, sm.c, W1, W1h, W1l, tid);
        } else if (vb < 484) {
            dev_convX(vb - 384, x, xh, xl, tid);
        } else if (vb < 884) {
            int i = vb - 484;
            dev_dist(i & 15, i >> 4, x, Dm, tid);
        } else {
            int idx = (vb - 884) * 256 + tid;
            if (idx < 16400) cnt[idx] = 0.0f;   // cnt[16] + G[16384] contiguous
        }
    }
    gbar(bar + 0);

    // ---- S1: gemm1 (312 vb) ----
    for (int vb = b0; vb < 312; vb += NBLK)
        dev_gemm1(vb, sm.g, xh, xl, W1h, W1l, A, tid);
    gbar(bar + 1);

    // ---- S2: accum (320 vb) ----
    for (int vb = b0; vb < 320; vb += NBLK)
        dev_accum(vb % 4, (vb / 4) % 5, vb / 20, A, Dm, b1, G, cnt, tid);
    gbar(bar + 2);

    // ---- S3: pooled (128 vb) ----
    for (int vb = b0; vb < 128; vb += NBLK)
        dev_pooled(vb % 8, vb / 8, sm.r, G, cnt, W2, b2, pooled, tid);
    gbar(bar + 3);

    // ---- S4: u (256 vb) ----
    for (int vb = b0; vb < 256; vb += NBLK)
        dev_u(vb % 16, vb / 16, sm.r, pooled, W3, b3, uu, tid);
    gbar(bar + 4);

    // ---- S5: o (128 vb) ----
    for (int vb = b0; vb < 128; vb += NBLK)
        dev_o(vb % 8, vb / 8, sm.r, uu, W4, b4, oo, tid);
    gbar(bar + 5);

    // ---- S6: score (16 vb) ----
    for (int vb = b0; vb < 16; vb += NBLK)
        dev_score(vb, sm.r, oo, Wc, bc, out, tid);
}

extern "C" void kernel_launch(void* const* d_in, const int* in_sizes, int n_in,
                              void* d_out, int out_size, void* d_ws, size_t ws_size,
                              hipStream_t stream)
{
    const float* x  = (const float*)d_in[0];
    const float* W1 = (const float*)d_in[1];
    const float* b1 = (const float*)d_in[2];
    const float* W2 = (const float*)d_in[3];
    const float* b2 = (const float*)d_in[4];
    const float* W3 = (const float*)d_in[5];
    const float* b3 = (const float*)d_in[6];
    const float* W4 = (const float*)d_in[7];
    const float* b4 = (const float*)d_in[8];
    const float* Wc = (const float*)d_in[9];
    const float* bc = (const float*)d_in[10];
    float* out = (float*)d_out;

    float* ws     = (float*)d_ws;
    float* Dm     = ws;                       // 10000
    float* cnt    = ws + 10000;               // 16   (cnt+G zeroed in S0)
    float* G      = ws + 10016;               // 16384
    float* A      = ws + 26400;               // 1228800
    float* pooled = A + 1228800;              // 8192
    float* uu     = pooled + 8192;            // 16384
    float* oo     = uu + 16384;               // 8192
    unsigned short* W1h = (unsigned short*)(oo + 8192);
    unsigned short* W1l = W1h + 3 * D2Z * DZ;
    unsigned short* xh  = W1l + 3 * D2Z * DZ;
    unsigned short* xl  = xh + 400 * DZ;
    int* bar = (int*)(xl + 400 * DZ);         // 8 ints

    hipMemsetAsync(bar, 0, 8 * sizeof(int), stream);

    k_mega<<<NBLK, 256, 0, stream>>>(
        x, W1, b1, W2, b2, W3, b3, W4, b4, Wc, bc, out,
        Dm, cnt, G, A, pooled, uu, oo, W1h, W1l, xh, xl, bar);
}

// Round 6
// 391.802 us; speedup vs baseline: 1.8606x; 1.8606x over previous
//
#include <hip/hip_runtime.h>
#include <math.h>

#define NT 16
#define NR 25
#define DZ 512
#define D2Z 1024
#define NC 64
#define NBLK 320

typedef short bf16x8 __attribute__((ext_vector_type(8)));
typedef float f32x4  __attribute__((ext_vector_type(4)));

#define TP  76   // convW LDS tile pitch (ushorts)
#define XP  72   // gemm xs pitch (ushorts) -> 144B rows, 16B aligned frags
#define WSP 72   // gemm ws pitch

static __device__ inline unsigned short f2bf(float v) {
    union { float f; unsigned u; } x; x.f = v;
    unsigned r = x.u + 0x7fffu + ((x.u >> 16) & 1u);
    return (unsigned short)(r >> 16);
}
static __device__ inline float bf2f(unsigned short h) {
    union { float f; unsigned u; } x; x.u = ((unsigned)h) << 16; return x.f;
}

struct SmemGemm {
    unsigned short xs_h[32 * XP], xs_l[32 * XP];
    unsigned short ws_h[128 * WSP], ws_l[128 * WSP];
};
struct SmemConv { unsigned short th[64 * TP], tl[64 * TP]; };
struct SmemRed  { float red[4][64]; };
union  alignas(16) Smem { SmemGemm g; SmemConv c; SmemRed r; };

// ---------------------------------------------------------------------------
// Grid barrier v2 (cache-benign): RELEASE arrive (one L2 writeback per
// block), RELAXED polls (no per-poll buffer_inv!), s_sleep to cut poll rate,
// then ONE acquire fence per block after convergence. The R5 version polled
// with ACQUIRE => buffer_inv per poll => continuous L1/L2 thrash, 100us/bar.
// ---------------------------------------------------------------------------
static __device__ inline void gbar(int* c)
{
    __syncthreads();
    if (threadIdx.x == 0) {
        __hip_atomic_fetch_add(c, 1, __ATOMIC_RELEASE, __HIP_MEMORY_SCOPE_AGENT);
        while (__hip_atomic_load(c, __ATOMIC_RELAXED, __HIP_MEMORY_SCOPE_AGENT) < NBLK)
            __builtin_amdgcn_s_sleep(16);
    }
    __syncthreads();
    __threadfence();   // single acquire: invalidate stale caches before reads
}

// ---------------------------------------------------------------------------
// S0a: convW virtual block (bx 0..23, by 0..15)
// ---------------------------------------------------------------------------
static __device__ void dev_convW(int bx, int by, SmemConv& sm,
                                 const float* __restrict__ W1,
                                 unsigned short* __restrict__ W1h,
                                 unsigned short* __restrict__ W1l, int tid)
{
    int r0 = bx * 64;
    int j0 = by * 64;
    int c  = r0 >> 9;
    int rb = r0 & 511;

    #pragma unroll
    for (int it = 0; it < 4; it++) {
        int rl = (tid >> 4) + it * 16;
        int jj = (tid & 15) * 4;
        float4 v = *(const float4*)(W1 + (size_t)(r0 + rl) * D2Z + j0 + jj);
        unsigned short h0 = f2bf(v.x), h1 = f2bf(v.y), h2 = f2bf(v.z), h3 = f2bf(v.w);
        sm.th[rl * TP + jj + 0] = h0; sm.tl[rl * TP + jj + 0] = f2bf(v.x - bf2f(h0));
        sm.th[rl * TP + jj + 1] = h1; sm.tl[rl * TP + jj + 1] = f2bf(v.y - bf2f(h1));
        sm.th[rl * TP + jj + 2] = h2; sm.tl[rl * TP + jj + 2] = f2bf(v.z - bf2f(h2));
        sm.th[rl * TP + jj + 3] = h3; sm.tl[rl * TP + jj + 3] = f2bf(v.w - bf2f(h3));
    }
    __syncthreads();

    #pragma unroll
    for (int it = 0; it < 4; it++) {
        int jl = (tid >> 4) + it * 16;
        int r4 = (tid & 15) * 4;
        ushort4 hv = make_ushort4(sm.th[(r4+0)*TP + jl], sm.th[(r4+1)*TP + jl],
                                  sm.th[(r4+2)*TP + jl], sm.th[(r4+3)*TP + jl]);
        ushort4 lv = make_ushort4(sm.tl[(r4+0)*TP + jl], sm.tl[(r4+1)*TP + jl],
                                  sm.tl[(r4+2)*TP + jl], sm.tl[(r4+3)*TP + jl]);
        size_t dst = ((size_t)c * D2Z + j0 + jl) * DZ + rb + r4;
        *(ushort4*)(W1h + dst) = hv;
        *(ushort4*)(W1l + dst) = lv;
    }
    __syncthreads();   // protect smem reuse by next virtual block
}

// ---------------------------------------------------------------------------
// S0b: convX virtual block (bid 0..99)
// ---------------------------------------------------------------------------
static __device__ void dev_convX(int bid, const float* __restrict__ x,
                                 unsigned short* __restrict__ xh,
                                 unsigned short* __restrict__ xl, int tid)
{
    size_t i8 = ((size_t)bid * 256 + tid) * 8;
    float4 a = *(const float4*)(x + i8);
    float4 b = *(const float4*)(x + i8 + 4);
    unsigned short h;
    ushort4 ha, hb, la, lb;
    h = f2bf(a.x); ha.x = h; la.x = f2bf(a.x - bf2f(h));
    h = f2bf(a.y); ha.y = h; la.y = f2bf(a.y - bf2f(h));
    h = f2bf(a.z); ha.z = h; la.z = f2bf(a.z - bf2f(h));
    h = f2bf(a.w); ha.w = h; la.w = f2bf(a.w - bf2f(h));
    h = f2bf(b.x); hb.x = h; lb.x = f2bf(b.x - bf2f(h));
    h = f2bf(b.y); hb.y = h; lb.y = f2bf(b.y - bf2f(h));
    h = f2bf(b.z); hb.z = h; lb.z = f2bf(b.z - bf2f(h));
    h = f2bf(b.w); hb.w = h; lb.w = f2bf(b.w - bf2f(h));
    *(ushort4*)(xh + i8)     = ha;  *(ushort4*)(xh + i8 + 4) = hb;
    *(ushort4*)(xl + i8)     = la;  *(ushort4*)(xl + i8 + 4) = lb;
}

// ---------------------------------------------------------------------------
// S0c: dist virtual block (k, a)
// ---------------------------------------------------------------------------
static __device__ void dev_dist(int k, int a, const float* __restrict__ x,
                                float* __restrict__ Dm, int tid)
{
    int lane = tid & 63;
    int w    = tid >> 6;
    const float* xk = x + (size_t)k * NR * DZ;

    const float4* xap = (const float4*)(xk + a * DZ);
    float4 a0 = xap[lane];
    float4 a1 = xap[lane + 64];

    float sa = a0.x*a0.x + a0.y*a0.y + a0.z*a0.z + a0.w*a0.w
             + a1.x*a1.x + a1.y*a1.y + a1.z*a1.z + a1.w*a1.w;
    #pragma unroll
    for (int off = 32; off; off >>= 1) sa += __shfl_xor(sa, off);
    float inva = 1.0f / sqrtf(sa);
    a0.x *= inva; a0.y *= inva; a0.z *= inva; a0.w *= inva;
    a1.x *= inva; a1.y *= inva; a1.z *= inva; a1.w *= inva;
    float sqa = a0.x*a0.x + a0.y*a0.y + a0.z*a0.z + a0.w*a0.w
              + a1.x*a1.x + a1.y*a1.y + a1.z*a1.z + a1.w*a1.w;
    #pragma unroll
    for (int off = 32; off; off >>= 1) sqa += __shfl_xor(sqa, off);

    for (int j = w; j < NR; j += 4) {
        const float4* xjp = (const float4*)(xk + j * DZ);
        float4 j0 = xjp[lane];
        float4 j1 = xjp[lane + 64];
        float sj = j0.x*j0.x + j0.y*j0.y + j0.z*j0.z + j0.w*j0.w
                 + j1.x*j1.x + j1.y*j1.y + j1.z*j1.z + j1.w*j1.w;
        #pragma unroll
        for (int off = 32; off; off >>= 1) sj += __shfl_xor(sj, off);
        float invj = 1.0f / sqrtf(sj);
        j0.x *= invj; j0.y *= invj; j0.z *= invj; j0.w *= invj;
        j1.x *= invj; j1.y *= invj; j1.z *= invj; j1.w *= invj;

        float sqj = j0.x*j0.x + j0.y*j0.y + j0.z*j0.z + j0.w*j0.w
                  + j1.x*j1.x + j1.y*j1.y + j1.z*j1.z + j1.w*j1.w;
        float dij = a0.x*j0.x + a0.y*j0.y + a0.z*j0.z + a0.w*j0.w
                  + a1.x*j1.x + a1.y*j1.y + a1.z*j1.z + a1.w*j1.w;
        #pragma unroll
        for (int off = 32; off; off >>= 1) {
            sqj += __shfl_xor(sqj, off);
            dij += __shfl_xor(dij, off);
        }
        float d2 = sqa + sqj - 2.0f * dij;
        float d  = sqrtf(fmaxf(d2, 0.0f));
        if (lane == 0) Dm[((size_t)k * NR + a) * NR + j] = d;
    }
}

// ---------------------------------------------------------------------------
// S1: split-bf16 MFMA gemm virtual block (bid 0..311)
// ---------------------------------------------------------------------------
static __device__ void dev_gemm1(int bid, SmemGemm& sm,
                                 const unsigned short* __restrict__ xh,
                                 const unsigned short* __restrict__ xl,
                                 const unsigned short* __restrict__ W1h,
                                 const unsigned short* __restrict__ W1l,
                                 float* __restrict__ A, int tid)
{
    int mt = bid / 24, nt = bid % 24;
    int m0 = mt * 32;
    int n0 = nt * 128;
    int c  = n0 >> 10;
    int j0 = n0 & 1023;

    int lane = tid & 63;
    int wv   = tid >> 6;
    int wm   = wv >> 1, wn = wv & 1;
    int q    = lane >> 4;
    int ln16 = lane & 15;

    f32x4 acc[4];
    #pragma unroll
    for (int t = 0; t < 4; t++) acc[t] = (f32x4){0.f, 0.f, 0.f, 0.f};

    int xrow = tid >> 3;
    int xkg  = (tid & 7) * 8;
    const uint4 zero4 = make_uint4(0u, 0u, 0u, 0u);

    for (int kk = 0; kk < 8; kk++) {
        int kbase = kk * 64;
        {
            int gm = m0 + xrow;
            uint4 vh = zero4, vl = zero4;
            if (gm < 400) {
                size_t off = (size_t)gm * DZ + kbase + xkg;
                vh = *(const uint4*)(xh + off);
                vl = *(const uint4*)(xl + off);
            }
            *(uint4*)&sm.xs_h[xrow * XP + xkg] = vh;
            *(uint4*)&sm.xs_l[xrow * XP + xkg] = vl;
        }
        #pragma unroll
        for (int it = 0; it < 4; it++) {
            int g  = tid + 256 * it;
            int nl = g >> 3;
            int kg = (g & 7) * 8;
            size_t off = ((size_t)c * D2Z + j0 + nl) * DZ + kbase + kg;
            *(uint4*)&sm.ws_h[nl * WSP + kg] = *(const uint4*)(W1h + off);
            *(uint4*)&sm.ws_l[nl * WSP + kg] = *(const uint4*)(W1l + off);
        }
        __syncthreads();

        #pragma unroll
        for (int ks = 0; ks < 2; ks++) {
            int ko = ks * 32 + q * 8;
            bf16x8 a_h = *(const bf16x8*)&sm.xs_h[(wm * 16 + ln16) * XP + ko];
            bf16x8 a_l = *(const bf16x8*)&sm.xs_l[(wm * 16 + ln16) * XP + ko];
            #pragma unroll
            for (int t = 0; t < 4; t++) {
                int nl = wn * 64 + t * 16 + ln16;
                bf16x8 b_h = *(const bf16x8*)&sm.ws_h[nl * WSP + ko];
                bf16x8 b_l = *(const bf16x8*)&sm.ws_l[nl * WSP + ko];
                acc[t] = __builtin_amdgcn_mfma_f32_16x16x32_bf16(a_h, b_h, acc[t], 0, 0, 0);
                acc[t] = __builtin_amdgcn_mfma_f32_16x16x32_bf16(a_h, b_l, acc[t], 0, 0, 0);
                acc[t] = __builtin_amdgcn_mfma_f32_16x16x32_bf16(a_l, b_h, acc[t], 0, 0, 0);
            }
        }
        __syncthreads();
    }

    #pragma unroll
    for (int t = 0; t < 4; t++) {
        int j = j0 + wn * 64 + t * 16 + ln16;
        #pragma unroll
        for (int r = 0; r < 4; r++) {
            int m = m0 + wm * 16 + q * 4 + r;
            if (m < 400) {
                int kT = m / 25, i = m % 25;
                A[(((size_t)kT * 3 + c) * NR + i) * D2Z + j] = acc[t][r];
            }
        }
    }
}

// ---------------------------------------------------------------------------
// S2: accum virtual block (jt, ag, k)
// ---------------------------------------------------------------------------
static __device__ void dev_accum(int jt, int ag, int k,
                                 const float* __restrict__ A,
                                 const float* __restrict__ Dm,
                                 const float* __restrict__ b1,
                                 float* __restrict__ G,
                                 float* __restrict__ cnt, int tid)
{
    int j = jt * 256 + tid;

    const float* Ab = A + (size_t)k * 75 * D2Z + j;
    float a2v[25], a3v[25];
    #pragma unroll
    for (int i = 0; i < 25; i++) a2v[i] = Ab[(size_t)(25 + i) * D2Z];
    #pragma unroll
    for (int i = 0; i < 25; i++) a3v[i] = Ab[(size_t)(50 + i) * D2Z];
    float b1v = b1[j];

    float acc = 0.0f, cntv = 0.0f;
    for (int qa = 0; qa < 5; qa++) {
        int a = ag * 5 + qa;
        float a1 = Ab[(size_t)a * D2Z];
        const float* Dk = Dm + ((size_t)k * NR + a) * NR;
        #pragma unroll
        for (int m = 0; m < 5; m++) {
            if (m == ag) continue;
            int p = qa + 5 * m;
            float dap = Dk[p];
            float s = a1 + a2v[p] + b1v;
            #pragma unroll
            for (int n = 0; n < 25; n++) {
                if ((n % 5) == qa) continue;
                float tm = Dk[n] - dap;
                bool sel = (tm > 0.0f) && (tm <= 0.8f);
                float pre = fmaxf(s + a3v[n], 0.0f);
                float msk = sel ? 1.0f : 0.0f;
                acc = fmaf(msk, pre, acc);
                cntv += msk;
            }
        }
    }

    atomicAdd(&G[(size_t)k * D2Z + j], acc);
    if (jt == 0 && tid == 0) atomicAdd(&cnt[k], cntv);
}

// ---------------------------------------------------------------------------
// S3..S6: tail virtual blocks
// ---------------------------------------------------------------------------
static __device__ void dev_pooled(int bx, int k, SmemRed& sm,
                                  const float* __restrict__ G,
                                  const float* __restrict__ cnt,
                                  const float* __restrict__ W2,
                                  const float* __restrict__ b2,
                                  float* __restrict__ pooled, int tid)
{
    int lane = tid & 63, kc = tid >> 6;
    int col = bx * 64 + lane;

    const float* Gk = G + (size_t)k * D2Z;
    float acc = 0.0f;
    int j0 = kc * 256;
    #pragma unroll 4
    for (int jj = j0; jj < j0 + 256; jj++)
        acc = fmaf(Gk[jj], W2[(size_t)jj * DZ + col], acc);

    sm.red[kc][lane] = acc;
    __syncthreads();
    if (tid < 64) {
        float s = sm.red[0][lane] + sm.red[1][lane] + sm.red[2][lane] + sm.red[3][lane];
        s += cnt[k] * b2[col];
        pooled[(size_t)k * DZ + col] = s;
    }
    __syncthreads();
}

static __device__ void dev_u(int bx, int k, SmemRed& sm,
                             const float* __restrict__ pooled,
                             const float* __restrict__ W3,
                             const float* __restrict__ b3,
                             float* __restrict__ u, int tid)
{
    int lane = tid & 63, kc = tid >> 6;
    int col = bx * 64 + lane;

    const float* Pk = pooled + (size_t)k * DZ;
    float acc = 0.0f;
    int s0 = kc * 128;
    #pragma unroll 4
    for (int s = s0; s < s0 + 128; s++)
        acc = fmaf(Pk[s], W3[(size_t)s * D2Z + col], acc);

    sm.red[kc][lane] = acc;
    __syncthreads();
    if (tid < 64) {
        float v = sm.red[0][lane] + sm.red[1][lane] + sm.red[2][lane] + sm.red[3][lane] + b3[col];
        u[(size_t)k * D2Z + col] = fmaxf(v, 0.0f);
    }
    __syncthreads();
}

static __device__ void dev_o(int bx, int k, SmemRed& sm,
                             const float* __restrict__ u,
                             const float* __restrict__ W4,
                             const float* __restrict__ b4,
                             float* __restrict__ o, int tid)
{
    int lane = tid & 63, kc = tid >> 6;
    int col = bx * 64 + lane;

    const float* Uk = u + (size_t)k * D2Z;
    float acc = 0.0f;
    int j0 = kc * 256;
    #pragma unroll 4
    for (int jj = j0; jj < j0 + 256; jj++)
        acc = fmaf(Uk[jj], W4[(size_t)jj * DZ + col], acc);

    sm.red[kc][lane] = acc;
    __syncthreads();
    if (tid < 64) {
        o[(size_t)k * DZ + col] = sm.red[0][lane] + sm.red[1][lane] + sm.red[2][lane]
                                + sm.red[3][lane] + b4[col];
    }
    __syncthreads();
}

static __device__ void dev_score(int k, SmemRed& sm,
                                 const float* __restrict__ o,
                                 const float* __restrict__ Wc,
                                 const float* __restrict__ bc,
                                 float* __restrict__ out, int tid)
{
    int oc = tid & 63, kc = tid >> 6;

    const float* Ok = o + (size_t)k * DZ;
    float acc = 0.0f;
    int r0 = kc * 128;
    #pragma unroll 4
    for (int rr = r0; rr < r0 + 128; rr++)
        acc = fmaf(Ok[rr], Wc[(size_t)rr * NC + oc], acc);

    sm.red[kc][oc] = acc;
    __syncthreads();
    if (tid < 64) {
        float sc = bc[tid] + sm.red[0][tid] + sm.red[1][tid] + sm.red[2][tid] + sm.red[3][tid];
        float m = sc;
        #pragma unroll
        for (int off = 32; off; off >>= 1) m = fmaxf(m, __shfl_xor(m, off));
        float e = expf(sc - m);
        float ss = e;
        #pragma unroll
        for (int off = 32; off; off >>= 1) ss += __shfl_xor(ss, off);
        out[k * NC + tid] = e / ss;
    }
    __syncthreads();
}

// ---------------------------------------------------------------------------
// Mega kernel, plain launch, manual global barriers. 320 blocks x 256.
// ---------------------------------------------------------------------------
__global__ __launch_bounds__(256, 2) void k_mega(
    const float* x,  const float* W1, const float* b1, const float* W2,
    const float* b2, const float* W3, const float* b3, const float* W4,
    const float* b4, const float* Wc, const float* bc, float* out,
    float* Dm, float* cnt, float* G, float* A,
    float* pooled, float* uu, float* oo,
    unsigned short* W1h, unsigned short* W1l,
    unsigned short* xh,  unsigned short* xl, int* bar)
{
    __shared__ Smem sm;
    int tid = threadIdx.x;
    int b0  = blockIdx.x;

    // ---- S0: convW (384) | convX (100) | dist (400) | zero G+cnt (65) ----
    for (int vb = b0; vb < 949; vb += NBLK) {
        if (vb < 384) {
            dev_convW(vb % 24, vb / 24, sm.c, W1, W1h, W1l, tid);
        } else if (vb < 484) {
            dev_convX(vb - 384, x, xh, xl, tid);
        } else if (vb < 884) {
            int i = vb - 484;
            dev_dist(i & 15, i >> 4, x, Dm, tid);
        } else {
            int idx = (vb - 884) * 256 + tid;
            if (idx < 16400) cnt[idx] = 0.0f;   // cnt[16] + G[16384] contiguous
        }
    }
    gbar(bar + 0);

    // ---- S1: gemm1 (312 vb) ----
    for (int vb = b0; vb < 312; vb += NBLK)
        dev_gemm1(vb, sm.g, xh, xl, W1h, W1l, A, tid);
    gbar(bar + 1);

    // ---- S2: accum (320 vb) ----
    for (int vb = b0; vb < 320; vb += NBLK)
        dev_accum(vb % 4, (vb / 4) % 5, vb / 20, A, Dm, b1, G, cnt, tid);
    gbar(bar + 2);

    // ---- S3: pooled (128 vb) ----
    for (int vb = b0; vb < 128; vb += NBLK)
        dev_pooled(vb % 8, vb / 8, sm.r, G, cnt, W2, b2, pooled, tid);
    gbar(bar + 3);

    // ---- S4: u (256 vb) ----
    for (int vb = b0; vb < 256; vb += NBLK)
        dev_u(vb % 16, vb / 16, sm.r, pooled, W3, b3, uu, tid);
    gbar(bar + 4);

    // ---- S5: o (128 vb) ----
    for (int vb = b0; vb < 128; vb += NBLK)
        dev_o(vb % 8, vb / 8, sm.r, uu, W4, b4, oo, tid);
    gbar(bar + 5);

    // ---- S6: score (16 vb) ----
    for (int vb = b0; vb < 16; vb += NBLK)
        dev_score(vb, sm.r, oo, Wc, bc, out, tid);
}

extern "C" void kernel_launch(void* const* d_in, const int* in_sizes, int n_in,
                              void* d_out, int out_size, void* d_ws, size_t ws_size,
                              hipStream_t stream)
{
    const float* x  = (const float*)d_in[0];
    const float* W1 = (const float*)d_in[1];
    const float* b1 = (const float*)d_in[2];
    const float* W2 = (const float*)d_in[3];
    const float* b2 = (const float*)d_in[4];
    const float* W3 = (const float*)d_in[5];
    const float* b3 = (const float*)d_in[6];
    const float* W4 = (const float*)d_in[7];
    const float* b4 = (const float*)d_in[8];
    const float* Wc = (const float*)d_in[9];
    const float* bc = (const float*)d_in[10];
    float* out = (float*)d_out;

    float* ws     = (float*)d_ws;
    float* Dm     = ws;                       // 10000
    float* cnt    = ws + 10000;               // 16   (cnt+G zeroed in S0)
    float* G      = ws + 10016;               // 16384
    float* A      = ws + 26400;               // 1228800
    float* pooled = A + 1228800;              // 8192
    float* uu     = pooled + 8192;            // 16384
    float* oo     = uu + 16384;               // 8192
    unsigned short* W1h = (unsigned short*)(oo + 8192);
    unsigned short* W1l = W1h + 3 * D2Z * DZ;
    unsigned short* xh  = W1l + 3 * D2Z * DZ;
    unsigned short* xl  = xh + 400 * DZ;
    int* bar = (int*)(xl + 400 * DZ);         // 8 ints

    hipMemsetAsync(bar, 0, 8 * sizeof(int), stream);

    k_mega<<<NBLK, 256, 0, stream>>>(
        x, W1, b1, W2, b2, W3, b3, W4, b4, Wc, bc, out,
        Dm, cnt, G, A, pooled, uu, oo, W1h, W1l, xh, xl, bar);
}

// Round 7
// 223.969 us; speedup vs baseline: 3.2548x; 1.7494x over previous
//
#include <hip/hip_runtime.h>
#include <math.h>

#define NT 16
#define NR 25
#define DZ 512
#define D2Z 1024
#define NC 64

typedef short bf16x8 __attribute__((ext_vector_type(8)));
typedef float f32x4  __attribute__((ext_vector_type(4)));

#define TP  76   // convW LDS tile pitch (ushorts)
#define XP  72   // gemm xs pitch (ushorts) -> 144B rows, 16B aligned frags
#define WSP 72   // gemm ws pitch

static __device__ inline unsigned short f2bf(float v) {
    union { float f; unsigned u; } x; x.f = v;
    unsigned r = x.u + 0x7fffu + ((x.u >> 16) & 1u);
    return (unsigned short)(r >> 16);
}
static __device__ inline float bf2f(unsigned short h) {
    union { float f; unsigned u; } x; x.u = ((unsigned)h) << 16; return x.f;
}

// ---------------------------------------------------------------------------
// k_prep: fused front-end, one dispatch. Blocks 0..383 convW transpose+split,
// 384..483 convX split, 484..883 pairwise distances, 884..948 zero G/cnt.
// All bodies identical to the verified R3 kernels.
// ---------------------------------------------------------------------------
__global__ __launch_bounds__(256) void k_prep(
    const float* __restrict__ x, const float* __restrict__ W1,
    unsigned short* __restrict__ W1h, unsigned short* __restrict__ W1l,
    unsigned short* __restrict__ xh,  unsigned short* __restrict__ xl,
    float* __restrict__ Dm, float* __restrict__ cntG)
{
    __shared__ unsigned short th[64 * TP], tl[64 * TP];
    int vb = blockIdx.x;
    int tid = threadIdx.x;

    if (vb < 384) {
        int r0 = (vb % 24) * 64;
        int j0 = (vb / 24) * 64;
        int c  = r0 >> 9;
        int rb = r0 & 511;

        #pragma unroll
        for (int it = 0; it < 4; it++) {
            int rl = (tid >> 4) + it * 16;
            int jj = (tid & 15) * 4;
            float4 v = *(const float4*)(W1 + (size_t)(r0 + rl) * D2Z + j0 + jj);
            unsigned short h0 = f2bf(v.x), h1 = f2bf(v.y), h2 = f2bf(v.z), h3 = f2bf(v.w);
            th[rl * TP + jj + 0] = h0; tl[rl * TP + jj + 0] = f2bf(v.x - bf2f(h0));
            th[rl * TP + jj + 1] = h1; tl[rl * TP + jj + 1] = f2bf(v.y - bf2f(h1));
            th[rl * TP + jj + 2] = h2; tl[rl * TP + jj + 2] = f2bf(v.z - bf2f(h2));
            th[rl * TP + jj + 3] = h3; tl[rl * TP + jj + 3] = f2bf(v.w - bf2f(h3));
        }
        __syncthreads();

        #pragma unroll
        for (int it = 0; it < 4; it++) {
            int jl = (tid >> 4) + it * 16;
            int r4 = (tid & 15) * 4;
            ushort4 hv = make_ushort4(th[(r4+0)*TP + jl], th[(r4+1)*TP + jl],
                                      th[(r4+2)*TP + jl], th[(r4+3)*TP + jl]);
            ushort4 lv = make_ushort4(tl[(r4+0)*TP + jl], tl[(r4+1)*TP + jl],
                                      tl[(r4+2)*TP + jl], tl[(r4+3)*TP + jl]);
            size_t dst = ((size_t)c * D2Z + j0 + jl) * DZ + rb + r4;
            *(ushort4*)(W1h + dst) = hv;
            *(ushort4*)(W1l + dst) = lv;
        }
    } else if (vb < 484) {
        size_t i8 = ((size_t)(vb - 384) * 256 + tid) * 8;
        float4 a = *(const float4*)(x + i8);
        float4 b = *(const float4*)(x + i8 + 4);
        unsigned short h;
        ushort4 ha, hb, la, lb;
        h = f2bf(a.x); ha.x = h; la.x = f2bf(a.x - bf2f(h));
        h = f2bf(a.y); ha.y = h; la.y = f2bf(a.y - bf2f(h));
        h = f2bf(a.z); ha.z = h; la.z = f2bf(a.z - bf2f(h));
        h = f2bf(a.w); ha.w = h; la.w = f2bf(a.w - bf2f(h));
        h = f2bf(b.x); hb.x = h; lb.x = f2bf(b.x - bf2f(h));
        h = f2bf(b.y); hb.y = h; lb.y = f2bf(b.y - bf2f(h));
        h = f2bf(b.z); hb.z = h; lb.z = f2bf(b.z - bf2f(h));
        h = f2bf(b.w); hb.w = h; lb.w = f2bf(b.w - bf2f(h));
        *(ushort4*)(xh + i8)     = ha;  *(ushort4*)(xh + i8 + 4) = hb;
        *(ushort4*)(xl + i8)     = la;  *(ushort4*)(xl + i8 + 4) = lb;
    } else if (vb < 884) {
        int i = vb - 484;
        int k = i & 15, a = i >> 4;
        int lane = tid & 63;
        int w    = tid >> 6;
        const float* xk = x + (size_t)k * NR * DZ;

        const float4* xap = (const float4*)(xk + a * DZ);
        float4 a0 = xap[lane];
        float4 a1 = xap[lane + 64];

        float sa = a0.x*a0.x + a0.y*a0.y + a0.z*a0.z + a0.w*a0.w
                 + a1.x*a1.x + a1.y*a1.y + a1.z*a1.z + a1.w*a1.w;
        #pragma unroll
        for (int off = 32; off; off >>= 1) sa += __shfl_xor(sa, off);
        float inva = 1.0f / sqrtf(sa);
        a0.x *= inva; a0.y *= inva; a0.z *= inva; a0.w *= inva;
        a1.x *= inva; a1.y *= inva; a1.z *= inva; a1.w *= inva;
        float sqa = a0.x*a0.x + a0.y*a0.y + a0.z*a0.z + a0.w*a0.w
                  + a1.x*a1.x + a1.y*a1.y + a1.z*a1.z + a1.w*a1.w;
        #pragma unroll
        for (int off = 32; off; off >>= 1) sqa += __shfl_xor(sqa, off);

        for (int j = w; j < NR; j += 4) {
            const float4* xjp = (const float4*)(xk + j * DZ);
            float4 j0 = xjp[lane];
            float4 j1 = xjp[lane + 64];
            float sj = j0.x*j0.x + j0.y*j0.y + j0.z*j0.z + j0.w*j0.w
                     + j1.x*j1.x + j1.y*j1.y + j1.z*j1.z + j1.w*j1.w;
            #pragma unroll
            for (int off = 32; off; off >>= 1) sj += __shfl_xor(sj, off);
            float invj = 1.0f / sqrtf(sj);
            j0.x *= invj; j0.y *= invj; j0.z *= invj; j0.w *= invj;
            j1.x *= invj; j1.y *= invj; j1.z *= invj; j1.w *= invj;

            float sqj = j0.x*j0.x + j0.y*j0.y + j0.z*j0.z + j0.w*j0.w
                      + j1.x*j1.x + j1.y*j1.y + j1.z*j1.z + j1.w*j1.w;
            float dij = a0.x*j0.x + a0.y*j0.y + a0.z*j0.z + a0.w*j0.w
                      + a1.x*j1.x + a1.y*j1.y + a1.z*j1.z + a1.w*j1.w;
            #pragma unroll
            for (int off = 32; off; off >>= 1) {
                sqj += __shfl_xor(sqj, off);
                dij += __shfl_xor(dij, off);
            }
            float d2 = sqa + sqj - 2.0f * dij;
            float d  = sqrtf(fmaxf(d2, 0.0f));
            if (lane == 0) Dm[((size_t)k * NR + a) * NR + j] = d;
        }
    } else {
        int idx = (vb - 884) * 256 + tid;
        if (idx < 16400) cntG[idx] = 0.0f;    // cnt[16] + G[16384] contiguous
    }
}

// ---------------------------------------------------------------------------
// k_gemm1: split-bf16 MFMA GEMM, software-pipelined (prefetch kk+1 into VGPR
// between the barriers so global latency overlaps ds_read+MFMA of kk).
// Tile 32m x 128n, BK=64, grid 312.
// ---------------------------------------------------------------------------
__global__ __launch_bounds__(256) void k_gemm1(const unsigned short* __restrict__ xh,
                                               const unsigned short* __restrict__ xl,
                                               const unsigned short* __restrict__ W1h,
                                               const unsigned short* __restrict__ W1l,
                                               float* __restrict__ A)
{
    __shared__ unsigned short xs_h[32 * XP], xs_l[32 * XP];
    __shared__ unsigned short ws_h[128 * WSP], ws_l[128 * WSP];

    int bid = blockIdx.x;
    int mt = bid / 24, nt = bid % 24;
    int m0 = mt * 32;
    int n0 = nt * 128;
    int c  = n0 >> 10;
    int j0 = n0 & 1023;

    int tid  = threadIdx.x;
    int lane = tid & 63;
    int wv   = tid >> 6;
    int wm   = wv >> 1, wn = wv & 1;
    int q    = lane >> 4;
    int ln16 = lane & 15;

    f32x4 acc[4];
    #pragma unroll
    for (int t = 0; t < 4; t++) acc[t] = (f32x4){0.f, 0.f, 0.f, 0.f};

    int xrow = tid >> 3;
    int xkg  = (tid & 7) * 8;
    int gm   = m0 + xrow;
    const uint4 zero4 = make_uint4(0u, 0u, 0u, 0u);

    uint4 rxh, rxl, rwh[4], rwl[4];

    // prefetch kk = 0
    {
        rxh = zero4; rxl = zero4;
        if (gm < 400) {
            size_t off = (size_t)gm * DZ + xkg;
            rxh = *(const uint4*)(xh + off);
            rxl = *(const uint4*)(xl + off);
        }
        #pragma unroll
        for (int it = 0; it < 4; it++) {
            int g  = tid + 256 * it;
            int nl = g >> 3;
            int kg = (g & 7) * 8;
            size_t off = ((size_t)c * D2Z + j0 + nl) * DZ + kg;
            rwh[it] = *(const uint4*)(W1h + off);
            rwl[it] = *(const uint4*)(W1l + off);
        }
    }

    for (int kk = 0; kk < 8; kk++) {
        // commit prefetched tile to LDS
        *(uint4*)&xs_h[xrow * XP + xkg] = rxh;
        *(uint4*)&xs_l[xrow * XP + xkg] = rxl;
        #pragma unroll
        for (int it = 0; it < 4; it++) {
            int g  = tid + 256 * it;
            int nl = g >> 3;
            int kg = (g & 7) * 8;
            *(uint4*)&ws_h[nl * WSP + kg] = rwh[it];
            *(uint4*)&ws_l[nl * WSP + kg] = rwl[it];
        }
        __syncthreads();

        // prefetch kk+1 while MFMAs run on kk
        if (kk < 7) {
            int kbase = (kk + 1) * 64;
            rxh = zero4; rxl = zero4;
            if (gm < 400) {
                size_t off = (size_t)gm * DZ + kbase + xkg;
                rxh = *(const uint4*)(xh + off);
                rxl = *(const uint4*)(xl + off);
            }
            #pragma unroll
            for (int it = 0; it < 4; it++) {
                int g  = tid + 256 * it;
                int nl = g >> 3;
                int kg = (g & 7) * 8;
                size_t off = ((size_t)c * D2Z + j0 + nl) * DZ + kbase + kg;
                rwh[it] = *(const uint4*)(W1h + off);
                rwl[it] = *(const uint4*)(W1l + off);
            }
        }

        #pragma unroll
        for (int ks = 0; ks < 2; ks++) {
            int ko = ks * 32 + q * 8;
            bf16x8 a_h = *(const bf16x8*)&xs_h[(wm * 16 + ln16) * XP + ko];
            bf16x8 a_l = *(const bf16x8*)&xs_l[(wm * 16 + ln16) * XP + ko];
            #pragma unroll
            for (int t = 0; t < 4; t++) {
                int nl = wn * 64 + t * 16 + ln16;
                bf16x8 b_h = *(const bf16x8*)&ws_h[nl * WSP + ko];
                bf16x8 b_l = *(const bf16x8*)&ws_l[nl * WSP + ko];
                acc[t] = __builtin_amdgcn_mfma_f32_16x16x32_bf16(a_h, b_h, acc[t], 0, 0, 0);
                acc[t] = __builtin_amdgcn_mfma_f32_16x16x32_bf16(a_h, b_l, acc[t], 0, 0, 0);
                acc[t] = __builtin_amdgcn_mfma_f32_16x16x32_bf16(a_l, b_h, acc[t], 0, 0, 0);
            }
        }
        __syncthreads();
    }

    #pragma unroll
    for (int t = 0; t < 4; t++) {
        int j = j0 + wn * 64 + t * 16 + ln16;
        #pragma unroll
        for (int r = 0; r < 4; r++) {
            int m = m0 + wm * 16 + q * 4 + r;
            if (m < 400) {
                int kT = m / 25, i = m % 25;
                A[(((size_t)kT * 3 + c) * NR + i) * D2Z + j] = acc[t][r];
            }
        }
    }
}

// ---------------------------------------------------------------------------
// k_accum: masked relu-accumulate; 5 anchors/block, atomics into zeroed G/cnt.
// Grid (4 jtiles, 5 anchor-groups, 16 tasks).
// ---------------------------------------------------------------------------
__global__ __launch_bounds__(256) void k_accum(const float* __restrict__ A,
                                               const float* __restrict__ Dm,
                                               const float* __restrict__ b1,
                                               float* __restrict__ G,
                                               float* __restrict__ cnt)
{
    int jt = blockIdx.x;
    int ag = blockIdx.y;
    int k  = blockIdx.z;
    int tid = threadIdx.x;
    int j = jt * 256 + tid;

    const float* Ab = A + (size_t)k * 75 * D2Z + j;
    float a2v[25], a3v[25];
    #pragma unroll
    for (int i = 0; i < 25; i++) a2v[i] = Ab[(size_t)(25 + i) * D2Z];
    #pragma unroll
    for (int i = 0; i < 25; i++) a3v[i] = Ab[(size_t)(50 + i) * D2Z];
    float b1v = b1[j];

    float acc = 0.0f, cntv = 0.0f;
    for (int qa = 0; qa < 5; qa++) {
        int a = ag * 5 + qa;
        float a1 = Ab[(size_t)a * D2Z];
        const float* Dk = Dm + ((size_t)k * NR + a) * NR;
        #pragma unroll
        for (int m = 0; m < 5; m++) {
            if (m == ag) continue;
            int p = qa + 5 * m;
            float dap = Dk[p];
            float s = a1 + a2v[p] + b1v;
            #pragma unroll
            for (int n = 0; n < 25; n++) {
                if ((n % 5) == qa) continue;
                float tm = Dk[n] - dap;
                bool sel = (tm > 0.0f) && (tm <= 0.8f);
                float pre = fmaxf(s + a3v[n], 0.0f);
                float msk = sel ? 1.0f : 0.0f;
                acc = fmaf(msk, pre, acc);
                cntv += msk;
            }
        }
    }

    atomicAdd(&G[(size_t)k * D2Z + j], acc);
    if (jt == 0 && tid == 0) atomicAdd(&cnt[k], cntv);
}

// ---------------------------------------------------------------------------
// Tail (verified R3 bodies).
// ---------------------------------------------------------------------------
__global__ __launch_bounds__(256) void k_pooled(const float* __restrict__ G,
                                                const float* __restrict__ cnt,
                                                const float* __restrict__ W2,
                                                const float* __restrict__ b2,
                                                float* __restrict__ pooled)
{
    int bx = blockIdx.x, k = blockIdx.y;
    int tid = threadIdx.x, lane = tid & 63, kc = tid >> 6;
    int col = bx * 64 + lane;

    const float* Gk = G + (size_t)k * D2Z;
    float acc = 0.0f;
    int j0 = kc * 256;
    #pragma unroll 4
    for (int jj = j0; jj < j0 + 256; jj++)
        acc = fmaf(Gk[jj], W2[(size_t)jj * DZ + col], acc);

    __shared__ float red[4][64];
    red[kc][lane] = acc;
    __syncthreads();
    if (tid < 64) {
        float s = red[0][lane] + red[1][lane] + red[2][lane] + red[3][lane];
        s += cnt[k] * b2[col];
        pooled[(size_t)k * DZ + col] = s;
    }
}

__global__ __launch_bounds__(256) void k_u(const float* __restrict__ pooled,
                                           const float* __restrict__ W3,
                                           const float* __restrict__ b3,
                                           float* __restrict__ u)
{
    int bx = blockIdx.x, k = blockIdx.y;
    int tid = threadIdx.x, lane = tid & 63, kc = tid >> 6;
    int col = bx * 64 + lane;

    const float* Pk = pooled + (size_t)k * DZ;
    float acc = 0.0f;
    int s0 = kc * 128;
    #pragma unroll 4
    for (int s = s0; s < s0 + 128; s++)
        acc = fmaf(Pk[s], W3[(size_t)s * D2Z + col], acc);

    __shared__ float red[4][64];
    red[kc][lane] = acc;
    __syncthreads();
    if (tid < 64) {
        float v = red[0][lane] + red[1][lane] + red[2][lane] + red[3][lane] + b3[col];
        u[(size_t)k * D2Z + col] = fmaxf(v, 0.0f);
    }
}

__global__ __launch_bounds__(256) void k_o(const float* __restrict__ u,
                                           const float* __restrict__ W4,
                                           const float* __restrict__ b4,
                                           float* __restrict__ o)
{
    int bx = blockIdx.x, k = blockIdx.y;
    int tid = threadIdx.x, lane = tid & 63, kc = tid >> 6;
    int col = bx * 64 + lane;

    const float* Uk = u + (size_t)k * D2Z;
    float acc = 0.0f;
    int j0 = kc * 256;
    #pragma unroll 4
    for (int jj = j0; jj < j0 + 256; jj++)
        acc = fmaf(Uk[jj], W4[(size_t)jj * DZ + col], acc);

    __shared__ float red[4][64];
    red[kc][lane] = acc;
    __syncthreads();
    if (tid < 64) {
        o[(size_t)k * DZ + col] = red[0][lane] + red[1][lane] + red[2][lane]
                                + red[3][lane] + b4[col];
    }
}

__global__ __launch_bounds__(256) void k_score(const float* __restrict__ o,
                                               const float* __restrict__ Wc,
                                               const float* __restrict__ bc,
                                               float* __restrict__ out)
{
    int k = blockIdx.x;
    int tid = threadIdx.x, oc = tid & 63, kc = tid >> 6;

    const float* Ok = o + (size_t)k * DZ;
    float acc = 0.0f;
    int r0 = kc * 128;
    #pragma unroll 4
    for (int rr = r0; rr < r0 + 128; rr++)
        acc = fmaf(Ok[rr], Wc[(size_t)rr * NC + oc], acc);

    __shared__ float red[4][64];
    red[kc][oc] = acc;
    __syncthreads();
    if (tid < 64) {
        float sc = bc[tid] + red[0][tid] + red[1][tid] + red[2][tid] + red[3][tid];
        float m = sc;
        #pragma unroll
        for (int off = 32; off; off >>= 1) m = fmaxf(m, __shfl_xor(m, off));
        float e = expf(sc - m);
        float ss = e;
        #pragma unroll
        for (int off = 32; off; off >>= 1) ss += __shfl_xor(ss, off);
        out[k * NC + tid] = e / ss;
    }
}

extern "C" void kernel_launch(void* const* d_in, const int* in_sizes, int n_in,
                              void* d_out, int out_size, void* d_ws, size_t ws_size,
                              hipStream_t stream)
{
    const float* x  = (const float*)d_in[0];
    const float* W1 = (const float*)d_in[1];
    const float* b1 = (const float*)d_in[2];
    const float* W2 = (const float*)d_in[3];
    const float* b2 = (const float*)d_in[4];
    const float* W3 = (const float*)d_in[5];
    const float* b3 = (const float*)d_in[6];
    const float* W4 = (const float*)d_in[7];
    const float* b4 = (const float*)d_in[8];
    const float* Wc = (const float*)d_in[9];
    const float* bc = (const float*)d_in[10];
    float* out = (float*)d_out;

    float* ws     = (float*)d_ws;
    float* Dm     = ws;                       // 10000
    float* cnt    = ws + 10000;               // 16   (cnt+G zeroed in k_prep)
    float* G      = ws + 10016;               // 16384
    float* A      = ws + 26400;               // 1228800
    float* pooled = A + 1228800;              // 8192
    float* uu     = pooled + 8192;            // 16384
    float* oo     = uu + 16384;               // 8192
    unsigned short* W1h = (unsigned short*)(oo + 8192);
    unsigned short* W1l = W1h + 3 * D2Z * DZ;
    unsigned short* xh  = W1l + 3 * D2Z * DZ;
    unsigned short* xl  = xh + 400 * DZ;

    k_prep  <<<949,             256, 0, stream>>>(x, W1, W1h, W1l, xh, xl, Dm, cnt);
    k_gemm1 <<<312,             256, 0, stream>>>(xh, xl, W1h, W1l, A);
    k_accum <<<dim3(4, 5, NT),  256, 0, stream>>>(A, Dm, b1, G, cnt);
    k_pooled<<<dim3(8, NT),     256, 0, stream>>>(G, cnt, W2, b2, pooled);
    k_u     <<<dim3(16, NT),    256, 0, stream>>>(pooled, W3, b3, uu);
    k_o     <<<dim3(8, NT),     256, 0, stream>>>(uu, W4, b4, oo);
    k_score <<<NT,              256, 0, stream>>>(oo, Wc, bc, out);
}

// Round 8
// 187.495 us; speedup vs baseline: 3.8879x; 1.1945x over previous
//
#include <hip/hip_runtime.h>
#include <math.h>

#define NT 16
#define NR 25
#define DZ 512
#define D2Z 1024
#define NC 64

typedef short bf16x8 __attribute__((ext_vector_type(8)));
typedef float f32x4  __attribute__((ext_vector_type(4)));

#define TP  76   // convW LDS tile pitch (ushorts)
#define XP  72   // fused xs/ws pitch (ushorts): 144B rows, 16B-aligned frags
#define CP  68   // C tile pitch (floats)

static __device__ inline unsigned short f2bf(float v) {
    union { float f; unsigned u; } x; x.f = v;
    unsigned r = x.u + 0x7fffu + ((x.u >> 16) & 1u);
    return (unsigned short)(r >> 16);
}
static __device__ inline float bf2f(unsigned short h) {
    union { float f; unsigned u; } x; x.u = ((unsigned)h) << 16; return x.f;
}

// ---------------------------------------------------------------------------
// k_prep: fused front-end. Blocks 0..383 convW transpose+split, 384..483
// convX split, 484..883 pairwise distances. (G/cnt zeroing no longer needed.)
// ---------------------------------------------------------------------------
__global__ __launch_bounds__(256) void k_prep(
    const float* __restrict__ x, const float* __restrict__ W1,
    unsigned short* __restrict__ W1h, unsigned short* __restrict__ W1l,
    unsigned short* __restrict__ xh,  unsigned short* __restrict__ xl,
    float* __restrict__ Dm)
{
    __shared__ unsigned short th[64 * TP], tl[64 * TP];
    int vb = blockIdx.x;
    int tid = threadIdx.x;

    if (vb < 384) {
        int r0 = (vb % 24) * 64;
        int j0 = (vb / 24) * 64;
        int c  = r0 >> 9;
        int rb = r0 & 511;

        #pragma unroll
        for (int it = 0; it < 4; it++) {
            int rl = (tid >> 4) + it * 16;
            int jj = (tid & 15) * 4;
            float4 v = *(const float4*)(W1 + (size_t)(r0 + rl) * D2Z + j0 + jj);
            unsigned short h0 = f2bf(v.x), h1 = f2bf(v.y), h2 = f2bf(v.z), h3 = f2bf(v.w);
            th[rl * TP + jj + 0] = h0; tl[rl * TP + jj + 0] = f2bf(v.x - bf2f(h0));
            th[rl * TP + jj + 1] = h1; tl[rl * TP + jj + 1] = f2bf(v.y - bf2f(h1));
            th[rl * TP + jj + 2] = h2; tl[rl * TP + jj + 2] = f2bf(v.z - bf2f(h2));
            th[rl * TP + jj + 3] = h3; tl[rl * TP + jj + 3] = f2bf(v.w - bf2f(h3));
        }
        __syncthreads();

        #pragma unroll
        for (int it = 0; it < 4; it++) {
            int jl = (tid >> 4) + it * 16;
            int r4 = (tid & 15) * 4;
            ushort4 hv = make_ushort4(th[(r4+0)*TP + jl], th[(r4+1)*TP + jl],
                                      th[(r4+2)*TP + jl], th[(r4+3)*TP + jl]);
            ushort4 lv = make_ushort4(tl[(r4+0)*TP + jl], tl[(r4+1)*TP + jl],
                                      tl[(r4+2)*TP + jl], tl[(r4+3)*TP + jl]);
            size_t dst = ((size_t)c * D2Z + j0 + jl) * DZ + rb + r4;
            *(ushort4*)(W1h + dst) = hv;
            *(ushort4*)(W1l + dst) = lv;
        }
    } else if (vb < 484) {
        size_t i8 = ((size_t)(vb - 384) * 256 + tid) * 8;
        float4 a = *(const float4*)(x + i8);
        float4 b = *(const float4*)(x + i8 + 4);
        unsigned short h;
        ushort4 ha, hb, la, lb;
        h = f2bf(a.x); ha.x = h; la.x = f2bf(a.x - bf2f(h));
        h = f2bf(a.y); ha.y = h; la.y = f2bf(a.y - bf2f(h));
        h = f2bf(a.z); ha.z = h; la.z = f2bf(a.z - bf2f(h));
        h = f2bf(a.w); ha.w = h; la.w = f2bf(a.w - bf2f(h));
        h = f2bf(b.x); hb.x = h; lb.x = f2bf(b.x - bf2f(h));
        h = f2bf(b.y); hb.y = h; lb.y = f2bf(b.y - bf2f(h));
        h = f2bf(b.z); hb.z = h; lb.z = f2bf(b.z - bf2f(h));
        h = f2bf(b.w); hb.w = h; lb.w = f2bf(b.w - bf2f(h));
        *(ushort4*)(xh + i8)     = ha;  *(ushort4*)(xh + i8 + 4) = hb;
        *(ushort4*)(xl + i8)     = la;  *(ushort4*)(xl + i8 + 4) = lb;
    } else {
        int i = vb - 484;
        int k = i & 15, a = i >> 4;
        int lane = tid & 63;
        int w    = tid >> 6;
        const float* xk = x + (size_t)k * NR * DZ;

        const float4* xap = (const float4*)(xk + a * DZ);
        float4 a0 = xap[lane];
        float4 a1 = xap[lane + 64];

        float sa = a0.x*a0.x + a0.y*a0.y + a0.z*a0.z + a0.w*a0.w
                 + a1.x*a1.x + a1.y*a1.y + a1.z*a1.z + a1.w*a1.w;
        #pragma unroll
        for (int off = 32; off; off >>= 1) sa += __shfl_xor(sa, off);
        float inva = 1.0f / sqrtf(sa);
        a0.x *= inva; a0.y *= inva; a0.z *= inva; a0.w *= inva;
        a1.x *= inva; a1.y *= inva; a1.z *= inva; a1.w *= inva;
        float sqa = a0.x*a0.x + a0.y*a0.y + a0.z*a0.z + a0.w*a0.w
                  + a1.x*a1.x + a1.y*a1.y + a1.z*a1.z + a1.w*a1.w;
        #pragma unroll
        for (int off = 32; off; off >>= 1) sqa += __shfl_xor(sqa, off);

        for (int j = w; j < NR; j += 4) {
            const float4* xjp = (const float4*)(xk + j * DZ);
            float4 j0 = xjp[lane];
            float4 j1 = xjp[lane + 64];
            float sj = j0.x*j0.x + j0.y*j0.y + j0.z*j0.z + j0.w*j0.w
                     + j1.x*j1.x + j1.y*j1.y + j1.z*j1.z + j1.w*j1.w;
            #pragma unroll
            for (int off = 32; off; off >>= 1) sj += __shfl_xor(sj, off);
            float invj = 1.0f / sqrtf(sj);
            j0.x *= invj; j0.y *= invj; j0.z *= invj; j0.w *= invj;
            j1.x *= invj; j1.y *= invj; j1.z *= invj; j1.w *= invj;

            float sqj = j0.x*j0.x + j0.y*j0.y + j0.z*j0.z + j0.w*j0.w
                      + j1.x*j1.x + j1.y*j1.y + j1.z*j1.z + j1.w*j1.w;
            float dij = a0.x*j0.x + a0.y*j0.y + a0.z*j0.z + a0.w*j0.w
                      + a1.x*j1.x + a1.y*j1.y + a1.z*j1.z + a1.w*j1.w;
            #pragma unroll
            for (int off = 32; off; off >>= 1) {
                sqj += __shfl_xor(sqj, off);
                dij += __shfl_xor(dij, off);
            }
            float d2 = sqa + sqj - 2.0f * dij;
            float d  = sqrtf(fmaxf(d2, 0.0f));
            if (lane == 0) Dm[((size_t)k * NR + a) * NR + j] = d;
        }
    }
}

// ---------------------------------------------------------------------------
// k_fused: per (task k, 64-col j-tile): 3 split-bf16 MFMA GEMMs (M=32pad,
// N=64, K=512, shared x A-operand) -> C tile [96][CP] in LDS -> in-block
// masked-relu triple accumulation -> direct G store (no atomics).
// Grid 256 = jt*16 + k (consecutive bids share the W1 j-tile => L2 reuse).
// MFMA accumulation order per element identical to R3 (same C bits -> same
// downstream behavior); only the G summation order changes (fp32-benign).
// ---------------------------------------------------------------------------
__global__ __launch_bounds__(256) void k_fused(
    const unsigned short* __restrict__ xh, const unsigned short* __restrict__ xl,
    const unsigned short* __restrict__ W1h, const unsigned short* __restrict__ W1l,
    const float* __restrict__ b1, const float* __restrict__ Dm,
    float* __restrict__ G)
{
    __shared__ unsigned short xs_h[32 * XP], xs_l[32 * XP];   // 4.5 KB each
    __shared__ unsigned short ws_h[64 * XP], ws_l[64 * XP];   // 9 KB each
    __shared__ float Ct[96 * CP];                             // 25.5 KB
    __shared__ float Dm_s[NR * NR];
    __shared__ float red[4][64];

    int bid = blockIdx.x;
    int jt = bid >> 4;          // 0..15
    int k  = bid & 15;          // task
    int j0 = jt * 64;

    int tid  = threadIdx.x;
    int lane = tid & 63;
    int w    = tid >> 6;        // wave 0..3
    int q    = lane >> 4;
    int ln16 = lane & 15;

    // stage Dm for this task (used by accum phase)
    for (int idx = tid; idx < NR * NR; idx += 256)
        Dm_s[idx] = Dm[(size_t)k * NR * NR + idx];

    int xrow = tid >> 3;              // 0..31
    int xkg  = (tid & 7) * 8;
    const uint4 zero4 = make_uint4(0u, 0u, 0u, 0u);

    for (int c = 0; c < 3; c++) {
        f32x4 acc0 = (f32x4){0.f,0.f,0.f,0.f};
        f32x4 acc1 = (f32x4){0.f,0.f,0.f,0.f};

        for (int kk = 0; kk < 8; kk++) {
            int kbase = kk * 64;
            // stage x tile (32 rows, rows >=25 zero)
            {
                uint4 vh = zero4, vl = zero4;
                if (xrow < NR) {
                    size_t off = ((size_t)k * NR + xrow) * DZ + kbase + xkg;
                    vh = *(const uint4*)(xh + off);
                    vl = *(const uint4*)(xl + off);
                }
                *(uint4*)&xs_h[xrow * XP + xkg] = vh;
                *(uint4*)&xs_l[xrow * XP + xkg] = vl;
            }
            // stage W tile (64 n-rows x 64 k)
            #pragma unroll
            for (int it = 0; it < 2; it++) {
                int g  = tid + 256 * it;      // 0..511
                int nl = g >> 3;              // 0..63
                int kg = (g & 7) * 8;
                size_t off = ((size_t)(c << 10) + j0 + nl) * DZ + kbase + kg;
                *(uint4*)&ws_h[nl * XP + kg] = *(const uint4*)(W1h + off);
                *(uint4*)&ws_l[nl * XP + kg] = *(const uint4*)(W1l + off);
            }
            __syncthreads();

            #pragma unroll
            for (int ks = 0; ks < 2; ks++) {
                int ko = ks * 32 + q * 8;
                bf16x8 b_h = *(const bf16x8*)&ws_h[(w * 16 + ln16) * XP + ko];
                bf16x8 b_l = *(const bf16x8*)&ws_l[(w * 16 + ln16) * XP + ko];
                {
                    bf16x8 a_h = *(const bf16x8*)&xs_h[ln16 * XP + ko];
                    bf16x8 a_l = *(const bf16x8*)&xs_l[ln16 * XP + ko];
                    acc0 = __builtin_amdgcn_mfma_f32_16x16x32_bf16(a_h, b_h, acc0, 0, 0, 0);
                    acc0 = __builtin_amdgcn_mfma_f32_16x16x32_bf16(a_h, b_l, acc0, 0, 0, 0);
                    acc0 = __builtin_amdgcn_mfma_f32_16x16x32_bf16(a_l, b_h, acc0, 0, 0, 0);
                }
                {
                    bf16x8 a_h = *(const bf16x8*)&xs_h[(16 + ln16) * XP + ko];
                    bf16x8 a_l = *(const bf16x8*)&xs_l[(16 + ln16) * XP + ko];
                    acc1 = __builtin_amdgcn_mfma_f32_16x16x32_bf16(a_h, b_h, acc1, 0, 0, 0);
                    acc1 = __builtin_amdgcn_mfma_f32_16x16x32_bf16(a_h, b_l, acc1, 0, 0, 0);
                    acc1 = __builtin_amdgcn_mfma_f32_16x16x32_bf16(a_l, b_h, acc1, 0, 0, 0);
                }
            }
            __syncthreads();
        }

        // epilogue: C rows for this c slice. col=lane&15 (+wave*16),
        // row=quad*4+reg (verified C/D mapping).
        int col = w * 16 + ln16;
        #pragma unroll
        for (int r = 0; r < 4; r++) {
            Ct[(c * 32 + q * 4 + r) * CP + col]      = acc0[r];
            Ct[(c * 32 + 16 + q * 4 + r) * CP + col] = acc1[r];
        }
    }
    __syncthreads();

    // ---- in-block accum: thread = (column j, valid-m index h) ----
    int j = tid & 63;
    int h = tid >> 6;      // 0..3 -> picks the h-th valid m (m != a/5)
    float b1v = b1[j0 + j];

    float a2v[NR], a3v[NR];
    #pragma unroll
    for (int i = 0; i < NR; i++) a2v[i] = Ct[(32 + i) * CP + j];
    #pragma unroll
    for (int i = 0; i < NR; i++) a3v[i] = Ct[(64 + i) * CP + j];

    float acc = 0.0f;
    #pragma unroll
    for (int a = 0; a < NR; a++) {
        const int qa = a % 5, mdiv = a / 5;
        int m = h + (h >= mdiv);
        int p = qa + 5 * m;
        float a1  = Ct[a * CP + j];
        float dap = Dm_s[a * NR + p];
        float s = a1 + a2v[p] + b1v;
        #pragma unroll
        for (int ng = 0; ng < 5; ng++) {
            #pragma unroll
            for (int o = 0; o < 4; o++) {
                int n = ng * 5 + o + (o >= qa);
                float tm = Dm_s[a * NR + n] - dap;
                bool sel = (tm > 0.0f) && (tm <= 0.8f);
                float pre = fmaxf(s + a3v[n], 0.0f);
                float msk = sel ? 1.0f : 0.0f;
                acc = fmaf(msk, pre, acc);
            }
        }
    }
    red[h][j] = acc;
    __syncthreads();
    if (tid < 64)
        G[(size_t)k * D2Z + j0 + tid] = red[0][tid] + red[1][tid]
                                      + red[2][tid] + red[3][tid];
}

// ---------------------------------------------------------------------------
// k_pooled: pooled[k][col] = G[k]·W2[:,col] + cnt[k]*b2[col].
// cnt recomputed locally from Dm (exact integer sum, no atomics needed).
// ---------------------------------------------------------------------------
__global__ __launch_bounds__(256) void k_pooled(const float* __restrict__ G,
                                                const float* __restrict__ Dm,
                                                const float* __restrict__ W2,
                                                const float* __restrict__ b2,
                                                float* __restrict__ pooled)
{
    int bx = blockIdx.x, k = blockIdx.y;
    int tid = threadIdx.x, lane = tid & 63, kc = tid >> 6;
    int col = bx * 64 + lane;

    // local cnt from Dm: 2000 triples over 256 threads
    const float* Dk = Dm + (size_t)k * NR * NR;
    float cntv = 0.0f;
    for (int idx = tid; idx < 2000; idx += 256) {
        int a   = idx / 80;
        int rem = idx - a * 80;
        int mi  = rem / 20;
        int nn  = rem - mi * 20;
        int qa = a % 5, mdiv = a / 5;
        int m = mi + (mi >= mdiv);
        int p = qa + 5 * m;
        int ng = nn >> 2, o = nn & 3;
        int n = ng * 5 + o + (o >= qa);
        float tm = Dk[a * NR + n] - Dk[a * NR + p];
        cntv += ((tm > 0.0f) && (tm <= 0.8f)) ? 1.0f : 0.0f;
    }
    #pragma unroll
    for (int off = 32; off; off >>= 1) cntv += __shfl_xor(cntv, off);

    __shared__ float red[4][64];
    __shared__ float cred[4];
    if (lane == 0) cred[kc] = cntv;

    const float* Gk = G + (size_t)k * D2Z;
    float acc = 0.0f;
    int j0 = kc * 256;
    #pragma unroll 4
    for (int jj = j0; jj < j0 + 256; jj++)
        acc = fmaf(Gk[jj], W2[(size_t)jj * DZ + col], acc);

    red[kc][lane] = acc;
    __syncthreads();
    if (tid < 64) {
        float cnt = cred[0] + cred[1] + cred[2] + cred[3];
        float s = red[0][lane] + red[1][lane] + red[2][lane] + red[3][lane];
        s += cnt * b2[col];
        pooled[(size_t)k * DZ + col] = s;
    }
}

__global__ __launch_bounds__(256) void k_u(const float* __restrict__ pooled,
                                           const float* __restrict__ W3,
                                           const float* __restrict__ b3,
                                           float* __restrict__ u)
{
    int bx = blockIdx.x, k = blockIdx.y;
    int tid = threadIdx.x, lane = tid & 63, kc = tid >> 6;
    int col = bx * 64 + lane;

    const float* Pk = pooled + (size_t)k * DZ;
    float acc = 0.0f;
    int s0 = kc * 128;
    #pragma unroll 4
    for (int s = s0; s < s0 + 128; s++)
        acc = fmaf(Pk[s], W3[(size_t)s * D2Z + col], acc);

    __shared__ float red[4][64];
    red[kc][lane] = acc;
    __syncthreads();
    if (tid < 64) {
        float v = red[0][lane] + red[1][lane] + red[2][lane] + red[3][lane] + b3[col];
        u[(size_t)k * D2Z + col] = fmaxf(v, 0.0f);
    }
}

__global__ __launch_bounds__(256) void k_o(const float* __restrict__ u,
                                           const float* __restrict__ W4,
                                           const float* __restrict__ b4,
                                           float* __restrict__ o)
{
    int bx = blockIdx.x, k = blockIdx.y;
    int tid = threadIdx.x, lane = tid & 63, kc = tid >> 6;
    int col = bx * 64 + lane;

    const float* Uk = u + (size_t)k * D2Z;
    float acc = 0.0f;
    int j0 = kc * 256;
    #pragma unroll 4
    for (int jj = j0; jj < j0 + 256; jj++)
        acc = fmaf(Uk[jj], W4[(size_t)jj * DZ + col], acc);

    __shared__ float red[4][64];
    red[kc][lane] = acc;
    __syncthreads();
    if (tid < 64) {
        o[(size_t)k * DZ + col] = red[0][lane] + red[1][lane] + red[2][lane]
                                + red[3][lane] + b4[col];
    }
}

__global__ __launch_bounds__(256) void k_score(const float* __restrict__ o,
                                               const float* __restrict__ Wc,
                                               const float* __restrict__ bc,
                                               float* __restrict__ out)
{
    int k = blockIdx.x;
    int tid = threadIdx.x, oc = tid & 63, kc = tid >> 6;

    const float* Ok = o + (size_t)k * DZ;
    float acc = 0.0f;
    int r0 = kc * 128;
    #pragma unroll 4
    for (int rr = r0; rr < r0 + 128; rr++)
        acc = fmaf(Ok[rr], Wc[(size_t)rr * NC + oc], acc);

    __shared__ float red[4][64];
    red[kc][oc] = acc;
    __syncthreads();
    if (tid < 64) {
        float sc = bc[tid] + red[0][tid] + red[1][tid] + red[2][tid] + red[3][tid];
        float m = sc;
        #pragma unroll
        for (int off = 32; off; off >>= 1) m = fmaxf(m, __shfl_xor(m, off));
        float e = expf(sc - m);
        float ss = e;
        #pragma unroll
        for (int off = 32; off; off >>= 1) ss += __shfl_xor(ss, off);
        out[k * NC + tid] = e / ss;
    }
}

extern "C" void kernel_launch(void* const* d_in, const int* in_sizes, int n_in,
                              void* d_out, int out_size, void* d_ws, size_t ws_size,
                              hipStream_t stream)
{
    const float* x  = (const float*)d_in[0];
    const float* W1 = (const float*)d_in[1];
    const float* b1 = (const float*)d_in[2];
    const float* W2 = (const float*)d_in[3];
    const float* b2 = (const float*)d_in[4];
    const float* W3 = (const float*)d_in[5];
    const float* b3 = (const float*)d_in[6];
    const float* W4 = (const float*)d_in[7];
    const float* b4 = (const float*)d_in[8];
    const float* Wc = (const float*)d_in[9];
    const float* bc = (const float*)d_in[10];
    float* out = (float*)d_out;

    float* ws     = (float*)d_ws;
    float* Dm     = ws;                       // 10000
    float* G      = ws + 10016;               // 16384 (fully overwritten)
    float* pooled = ws + 26400;               // 8192
    float* uu     = pooled + 8192;            // 16384
    float* oo     = uu + 16384;               // 8192
    unsigned short* W1h = (unsigned short*)(oo + 8192);
    unsigned short* W1l = W1h + 3 * D2Z * DZ;
    unsigned short* xh  = W1l + 3 * D2Z * DZ;
    unsigned short* xl  = xh + 400 * DZ;

    k_prep  <<<884,            256, 0, stream>>>(x, W1, W1h, W1l, xh, xl, Dm);
    k_fused <<<256,            256, 0, stream>>>(xh, xl, W1h, W1l, b1, Dm, G);
    k_pooled<<<dim3(8, NT),    256, 0, stream>>>(G, Dm, W2, b2, pooled);
    k_u     <<<dim3(16, NT),   256, 0, stream>>>(pooled, W3, b3, uu);
    k_o     <<<dim3(8, NT),    256, 0, stream>>>(uu, W4, b4, oo);
    k_score <<<NT,             256, 0, stream>>>(oo, Wc, bc, out);
}

// Round 9
// 153.447 us; speedup vs baseline: 4.7506x; 1.2219x over previous
//
#include <hip/hip_runtime.h>
#include <math.h>

#define NT 16
#define NR 25
#define DZ 512
#define D2Z 1024
#define NC 64

typedef short bf16x8 __attribute__((ext_vector_type(8)));
typedef float f32x4  __attribute__((ext_vector_type(4)));

#define TP  76    // convW LDS tile pitch (ushorts)
#define XP2 136   // fused xs/ws pitch for BK=128 (ushorts): 272B rows
#define CP  68    // C tile pitch (floats)

static __device__ inline unsigned short f2bf(float v) {
    union { float f; unsigned u; } x; x.f = v;
    unsigned r = x.u + 0x7fffu + ((x.u >> 16) & 1u);
    return (unsigned short)(r >> 16);
}
static __device__ inline float bf2f(unsigned short h) {
    union { float f; unsigned u; } x; x.u = ((unsigned)h) << 16; return x.f;
}

// ---------------------------------------------------------------------------
// k_prep: fused front-end (verified R8 body). Blocks 0..383 convW
// transpose+split, 384..483 convX split, 484..883 pairwise distances.
// ---------------------------------------------------------------------------
__global__ __launch_bounds__(256) void k_prep(
    const float* __restrict__ x, const float* __restrict__ W1,
    unsigned short* __restrict__ W1h, unsigned short* __restrict__ W1l,
    unsigned short* __restrict__ xh,  unsigned short* __restrict__ xl,
    float* __restrict__ Dm)
{
    __shared__ unsigned short th[64 * TP], tl[64 * TP];
    int vb = blockIdx.x;
    int tid = threadIdx.x;

    if (vb < 384) {
        int r0 = (vb % 24) * 64;
        int j0 = (vb / 24) * 64;
        int c  = r0 >> 9;
        int rb = r0 & 511;

        #pragma unroll
        for (int it = 0; it < 4; it++) {
            int rl = (tid >> 4) + it * 16;
            int jj = (tid & 15) * 4;
            float4 v = *(const float4*)(W1 + (size_t)(r0 + rl) * D2Z + j0 + jj);
            unsigned short h0 = f2bf(v.x), h1 = f2bf(v.y), h2 = f2bf(v.z), h3 = f2bf(v.w);
            th[rl * TP + jj + 0] = h0; tl[rl * TP + jj + 0] = f2bf(v.x - bf2f(h0));
            th[rl * TP + jj + 1] = h1; tl[rl * TP + jj + 1] = f2bf(v.y - bf2f(h1));
            th[rl * TP + jj + 2] = h2; tl[rl * TP + jj + 2] = f2bf(v.z - bf2f(h2));
            th[rl * TP + jj + 3] = h3; tl[rl * TP + jj + 3] = f2bf(v.w - bf2f(h3));
        }
        __syncthreads();

        #pragma unroll
        for (int it = 0; it < 4; it++) {
            int jl = (tid >> 4) + it * 16;
            int r4 = (tid & 15) * 4;
            ushort4 hv = make_ushort4(th[(r4+0)*TP + jl], th[(r4+1)*TP + jl],
                                      th[(r4+2)*TP + jl], th[(r4+3)*TP + jl]);
            ushort4 lv = make_ushort4(tl[(r4+0)*TP + jl], tl[(r4+1)*TP + jl],
                                      tl[(r4+2)*TP + jl], tl[(r4+3)*TP + jl]);
            size_t dst = ((size_t)c * D2Z + j0 + jl) * DZ + rb + r4;
            *(ushort4*)(W1h + dst) = hv;
            *(ushort4*)(W1l + dst) = lv;
        }
    } else if (vb < 484) {
        size_t i8 = ((size_t)(vb - 384) * 256 + tid) * 8;
        float4 a = *(const float4*)(x + i8);
        float4 b = *(const float4*)(x + i8 + 4);
        unsigned short h;
        ushort4 ha, hb, la, lb;
        h = f2bf(a.x); ha.x = h; la.x = f2bf(a.x - bf2f(h));
        h = f2bf(a.y); ha.y = h; la.y = f2bf(a.y - bf2f(h));
        h = f2bf(a.z); ha.z = h; la.z = f2bf(a.z - bf2f(h));
        h = f2bf(a.w); ha.w = h; la.w = f2bf(a.w - bf2f(h));
        h = f2bf(b.x); hb.x = h; lb.x = f2bf(b.x - bf2f(h));
        h = f2bf(b.y); hb.y = h; lb.y = f2bf(b.y - bf2f(h));
        h = f2bf(b.z); hb.z = h; lb.z = f2bf(b.z - bf2f(h));
        h = f2bf(b.w); hb.w = h; lb.w = f2bf(b.w - bf2f(h));
        *(ushort4*)(xh + i8)     = ha;  *(ushort4*)(xh + i8 + 4) = hb;
        *(ushort4*)(xl + i8)     = la;  *(ushort4*)(xl + i8 + 4) = lb;
    } else {
        int i = vb - 484;
        int k = i & 15, a = i >> 4;
        int lane = tid & 63;
        int w    = tid >> 6;
        const float* xk = x + (size_t)k * NR * DZ;

        const float4* xap = (const float4*)(xk + a * DZ);
        float4 a0 = xap[lane];
        float4 a1 = xap[lane + 64];

        float sa = a0.x*a0.x + a0.y*a0.y + a0.z*a0.z + a0.w*a0.w
                 + a1.x*a1.x + a1.y*a1.y + a1.z*a1.z + a1.w*a1.w;
        #pragma unroll
        for (int off = 32; off; off >>= 1) sa += __shfl_xor(sa, off);
        float inva = 1.0f / sqrtf(sa);
        a0.x *= inva; a0.y *= inva; a0.z *= inva; a0.w *= inva;
        a1.x *= inva; a1.y *= inva; a1.z *= inva; a1.w *= inva;
        float sqa = a0.x*a0.x + a0.y*a0.y + a0.z*a0.z + a0.w*a0.w
                  + a1.x*a1.x + a1.y*a1.y + a1.z*a1.z + a1.w*a1.w;
        #pragma unroll
        for (int off = 32; off; off >>= 1) sqa += __shfl_xor(sqa, off);

        for (int j = w; j < NR; j += 4) {
            const float4* xjp = (const float4*)(xk + j * DZ);
            float4 j0 = xjp[lane];
            float4 j1 = xjp[lane + 64];
            float sj = j0.x*j0.x + j0.y*j0.y + j0.z*j0.z + j0.w*j0.w
                     + j1.x*j1.x + j1.y*j1.y + j1.z*j1.z + j1.w*j1.w;
            #pragma unroll
            for (int off = 32; off; off >>= 1) sj += __shfl_xor(sj, off);
            float invj = 1.0f / sqrtf(sj);
            j0.x *= invj; j0.y *= invj; j0.z *= invj; j0.w *= invj;
            j1.x *= invj; j1.y *= invj; j1.z *= invj; j1.w *= invj;

            float sqj = j0.x*j0.x + j0.y*j0.y + j0.z*j0.z + j0.w*j0.w
                      + j1.x*j1.x + j1.y*j1.y + j1.z*j1.z + j1.w*j1.w;
            float dij = a0.x*j0.x + a0.y*j0.y + a0.z*j0.z + a0.w*j0.w
                      + a1.x*j1.x + a1.y*j1.y + a1.z*j1.z + a1.w*j1.w;
            #pragma unroll
            for (int off = 32; off; off >>= 1) {
                sqj += __shfl_xor(sqj, off);
                dij += __shfl_xor(dij, off);
            }
            float d2 = sqa + sqj - 2.0f * dij;
            float d  = sqrtf(fmaxf(d2, 0.0f));
            if (lane == 0) Dm[((size_t)k * NR + a) * NR + j] = d;
        }
    }
}

// ---------------------------------------------------------------------------
// k_fused v2: per (task k, 64-col j-tile) GEMM+accum.
//  - XCD swizzle: bid = k*16 + jt  =>  all 16 blocks of one j-tile have
//    bid % 8 == jt % 8 -> same XCD -> W1 tile fetched into that L2 once.
//  - BK=128: 12 staging barriers instead of 24 (same bytes, half latency).
// MFMA order per element unchanged vs R8 (ascending 32-k chunks, [hh,hl,lh]).
// ---------------------------------------------------------------------------
__global__ __launch_bounds__(256) void k_fused(
    const unsigned short* __restrict__ xh, const unsigned short* __restrict__ xl,
    const unsigned short* __restrict__ W1h, const unsigned short* __restrict__ W1l,
    const float* __restrict__ b1, const float* __restrict__ Dm,
    float* __restrict__ G)
{
    __shared__ unsigned short xs_h[32 * XP2], xs_l[32 * XP2];   // 8.5 KB each
    __shared__ unsigned short ws_h[64 * XP2], ws_l[64 * XP2];   // 17 KB each
    __shared__ float Ct[96 * CP];                               // 26.1 KB
    __shared__ float Dm_s[NR * NR];
    __shared__ float red[4][64];

    int bid = blockIdx.x;
    int k  = bid >> 4;          // task
    int jt = bid & 15;          // j-tile -> XCD = jt % 8 for all k
    int j0 = jt * 64;

    int tid  = threadIdx.x;
    int lane = tid & 63;
    int w    = tid >> 6;
    int q    = lane >> 4;
    int ln16 = lane & 15;

    for (int idx = tid; idx < NR * NR; idx += 256)
        Dm_s[idx] = Dm[(size_t)k * NR * NR + idx];

    const uint4 zero4 = make_uint4(0u, 0u, 0u, 0u);

    for (int c = 0; c < 3; c++) {
        f32x4 acc0 = (f32x4){0.f,0.f,0.f,0.f};
        f32x4 acc1 = (f32x4){0.f,0.f,0.f,0.f};

        for (int kk = 0; kk < 4; kk++) {
            int kbase = kk * 128;
            // stage x chunk: 32 rows x 128 k (rows >= 25 zero)
            #pragma unroll
            for (int it = 0; it < 2; it++) {
                int g   = tid + 256 * it;      // 0..511
                int row = g >> 4;              // 0..31
                int kg  = (g & 15) * 8;
                uint4 vh = zero4, vl = zero4;
                if (row < NR) {
                    size_t off = ((size_t)k * NR + row) * DZ + kbase + kg;
                    vh = *(const uint4*)(xh + off);
                    vl = *(const uint4*)(xl + off);
                }
                *(uint4*)&xs_h[row * XP2 + kg] = vh;
                *(uint4*)&xs_l[row * XP2 + kg] = vl;
            }
            // stage W chunk: 64 n-rows x 128 k
            #pragma unroll
            for (int it = 0; it < 4; it++) {
                int g   = tid + 256 * it;      // 0..1023
                int row = g >> 4;              // 0..63
                int kg  = (g & 15) * 8;
                size_t off = ((size_t)(c << 10) + j0 + row) * DZ + kbase + kg;
                *(uint4*)&ws_h[row * XP2 + kg] = *(const uint4*)(W1h + off);
                *(uint4*)&ws_l[row * XP2 + kg] = *(const uint4*)(W1l + off);
            }
            __syncthreads();

            #pragma unroll
            for (int ks = 0; ks < 4; ks++) {
                int ko = ks * 32 + q * 8;
                bf16x8 b_h = *(const bf16x8*)&ws_h[(w * 16 + ln16) * XP2 + ko];
                bf16x8 b_l = *(const bf16x8*)&ws_l[(w * 16 + ln16) * XP2 + ko];
                {
                    bf16x8 a_h = *(const bf16x8*)&xs_h[ln16 * XP2 + ko];
                    bf16x8 a_l = *(const bf16x8*)&xs_l[ln16 * XP2 + ko];
                    acc0 = __builtin_amdgcn_mfma_f32_16x16x32_bf16(a_h, b_h, acc0, 0, 0, 0);
                    acc0 = __builtin_amdgcn_mfma_f32_16x16x32_bf16(a_h, b_l, acc0, 0, 0, 0);
                    acc0 = __builtin_amdgcn_mfma_f32_16x16x32_bf16(a_l, b_h, acc0, 0, 0, 0);
                }
                {
                    bf16x8 a_h = *(const bf16x8*)&xs_h[(16 + ln16) * XP2 + ko];
                    bf16x8 a_l = *(const bf16x8*)&xs_l[(16 + ln16) * XP2 + ko];
                    acc1 = __builtin_amdgcn_mfma_f32_16x16x32_bf16(a_h, b_h, acc1, 0, 0, 0);
                    acc1 = __builtin_amdgcn_mfma_f32_16x16x32_bf16(a_h, b_l, acc1, 0, 0, 0);
                    acc1 = __builtin_amdgcn_mfma_f32_16x16x32_bf16(a_l, b_h, acc1, 0, 0, 0);
                }
            }
            __syncthreads();
        }

        int col = w * 16 + ln16;
        #pragma unroll
        for (int r = 0; r < 4; r++) {
            Ct[(c * 32 + q * 4 + r) * CP + col]      = acc0[r];
            Ct[(c * 32 + 16 + q * 4 + r) * CP + col] = acc1[r];
        }
    }
    __syncthreads();

    // ---- in-block accum: thread = (column j, valid-m index h) ----
    int j = tid & 63;
    int h = tid >> 6;
    float b1v = b1[j0 + j];

    float a2v[NR], a3v[NR];
    #pragma unroll
    for (int i = 0; i < NR; i++) a2v[i] = Ct[(32 + i) * CP + j];
    #pragma unroll
    for (int i = 0; i < NR; i++) a3v[i] = Ct[(64 + i) * CP + j];

    float acc = 0.0f;
    #pragma unroll
    for (int a = 0; a < NR; a++) {
        const int qa = a % 5, mdiv = a / 5;
        int m = h + (h >= mdiv);
        int p = qa + 5 * m;
        float a1  = Ct[a * CP + j];
        float dap = Dm_s[a * NR + p];
        float s = a1 + a2v[p] + b1v;
        #pragma unroll
        for (int ng = 0; ng < 5; ng++) {
            #pragma unroll
            for (int o = 0; o < 4; o++) {
                int n = ng * 5 + o + (o >= qa);
                float tm = Dm_s[a * NR + n] - dap;
                bool sel = (tm > 0.0f) && (tm <= 0.8f);
                float pre = fmaxf(s + a3v[n], 0.0f);
                float msk = sel ? 1.0f : 0.0f;
                acc = fmaf(msk, pre, acc);
            }
        }
    }
    red[h][j] = acc;
    __syncthreads();
    if (tid < 64)
        G[(size_t)k * D2Z + j0 + tid] = red[0][tid] + red[1][tid]
                                      + red[2][tid] + red[3][tid];
}

// ---------------------------------------------------------------------------
// k_pooled: 4 independent accumulators + unroll -> 16 loads in flight.
// cnt recomputed locally from Dm (exact integer sum).
// ---------------------------------------------------------------------------
__global__ __launch_bounds__(256) void k_pooled(const float* __restrict__ G,
                                                const float* __restrict__ Dm,
                                                const float* __restrict__ W2,
                                                const float* __restrict__ b2,
                                                float* __restrict__ pooled)
{
    int bx = blockIdx.x, k = blockIdx.y;
    int tid = threadIdx.x, lane = tid & 63, kc = tid >> 6;
    int col = bx * 64 + lane;

    const float* Dk = Dm + (size_t)k * NR * NR;
    float cntv = 0.0f;
    for (int idx = tid; idx < 2000; idx += 256) {
        int a   = idx / 80;
        int rem = idx - a * 80;
        int mi  = rem / 20;
        int nn  = rem - mi * 20;
        int qa = a % 5, mdiv = a / 5;
        int m = mi + (mi >= mdiv);
        int p = qa + 5 * m;
        int ng = nn >> 2, o = nn & 3;
        int n = ng * 5 + o + (o >= qa);
        float tm = Dk[a * NR + n] - Dk[a * NR + p];
        cntv += ((tm > 0.0f) && (tm <= 0.8f)) ? 1.0f : 0.0f;
    }
    #pragma unroll
    for (int off = 32; off; off >>= 1) cntv += __shfl_xor(cntv, off);

    __shared__ float red[4][64];
    __shared__ float cred[4];
    if (lane == 0) cred[kc] = cntv;

    const float* Gk = G + (size_t)k * D2Z;
    float a0 = 0.f, a1 = 0.f, a2 = 0.f, a3 = 0.f;
    int j0 = kc * 256;
    #pragma unroll 4
    for (int jj = j0; jj < j0 + 256; jj += 4) {
        a0 = fmaf(Gk[jj+0], W2[(size_t)(jj+0) * DZ + col], a0);
        a1 = fmaf(Gk[jj+1], W2[(size_t)(jj+1) * DZ + col], a1);
        a2 = fmaf(Gk[jj+2], W2[(size_t)(jj+2) * DZ + col], a2);
        a3 = fmaf(Gk[jj+3], W2[(size_t)(jj+3) * DZ + col], a3);
    }
    red[kc][lane] = (a0 + a1) + (a2 + a3);
    __syncthreads();
    if (tid < 64) {
        float cnt = cred[0] + cred[1] + cred[2] + cred[3];
        float s = red[0][lane] + red[1][lane] + red[2][lane] + red[3][lane];
        s += cnt * b2[col];
        pooled[(size_t)k * DZ + col] = s;
    }
}

__global__ __launch_bounds__(256) void k_u(const float* __restrict__ pooled,
                                           const float* __restrict__ W3,
                                           const float* __restrict__ b3,
                                           float* __restrict__ u)
{
    int bx = blockIdx.x, k = blockIdx.y;
    int tid = threadIdx.x, lane = tid & 63, kc = tid >> 6;
    int col = bx * 64 + lane;

    const float* Pk = pooled + (size_t)k * DZ;
    float a0 = 0.f, a1 = 0.f, a2 = 0.f, a3 = 0.f;
    int s0 = kc * 128;
    #pragma unroll 4
    for (int s = s0; s < s0 + 128; s += 4) {
        a0 = fmaf(Pk[s+0], W3[(size_t)(s+0) * D2Z + col], a0);
        a1 = fmaf(Pk[s+1], W3[(size_t)(s+1) * D2Z + col], a1);
        a2 = fmaf(Pk[s+2], W3[(size_t)(s+2) * D2Z + col], a2);
        a3 = fmaf(Pk[s+3], W3[(size_t)(s+3) * D2Z + col], a3);
    }
    __shared__ float red[4][64];
    red[kc][lane] = (a0 + a1) + (a2 + a3);
    __syncthreads();
    if (tid < 64) {
        float v = red[0][lane] + red[1][lane] + red[2][lane] + red[3][lane] + b3[col];
        u[(size_t)k * D2Z + col] = fmaxf(v, 0.0f);
    }
}

__global__ __launch_bounds__(256) void k_o(const float* __restrict__ u,
                                           const float* __restrict__ W4,
                                           const float* __restrict__ b4,
                                           float* __restrict__ o)
{
    int bx = blockIdx.x, k = blockIdx.y;
    int tid = threadIdx.x, lane = tid & 63, kc = tid >> 6;
    int col = bx * 64 + lane;

    const float* Uk = u + (size_t)k * D2Z;
    float a0 = 0.f, a1 = 0.f, a2 = 0.f, a3 = 0.f;
    int j0 = kc * 256;
    #pragma unroll 4
    for (int jj = j0; jj < j0 + 256; jj += 4) {
        a0 = fmaf(Uk[jj+0], W4[(size_t)(jj+0) * DZ + col], a0);
        a1 = fmaf(Uk[jj+1], W4[(size_t)(jj+1) * DZ + col], a1);
        a2 = fmaf(Uk[jj+2], W4[(size_t)(jj+2) * DZ + col], a2);
        a3 = fmaf(Uk[jj+3], W4[(size_t)(jj+3) * DZ + col], a3);
    }
    __shared__ float red[4][64];
    red[kc][lane] = (a0 + a1) + (a2 + a3);
    __syncthreads();
    if (tid < 64) {
        o[(size_t)k * DZ + col] = red[0][lane] + red[1][lane] + red[2][lane]
                                + red[3][lane] + b4[col];
    }
}

__global__ __launch_bounds__(256) void k_score(const float* __restrict__ o,
                                               const float* __restrict__ Wc,
                                               const float* __restrict__ bc,
                                               float* __restrict__ out)
{
    int k = blockIdx.x;
    int tid = threadIdx.x, oc = tid & 63, kc = tid >> 6;

    const float* Ok = o + (size_t)k * DZ;
    float a0 = 0.f, a1 = 0.f, a2 = 0.f, a3 = 0.f;
    int r0 = kc * 128;
    #pragma unroll 4
    for (int rr = r0; rr < r0 + 128; rr += 4) {
        a0 = fmaf(Ok[rr+0], Wc[(size_t)(rr+0) * NC + oc], a0);
        a1 = fmaf(Ok[rr+1], Wc[(size_t)(rr+1) * NC + oc], a1);
        a2 = fmaf(Ok[rr+2], Wc[(size_t)(rr+2) * NC + oc], a2);
        a3 = fmaf(Ok[rr+3], Wc[(size_t)(rr+3) * NC + oc], a3);
    }
    __shared__ float red[4][64];
    red[kc][oc] = (a0 + a1) + (a2 + a3);
    __syncthreads();
    if (tid < 64) {
        float sc = bc[tid] + red[0][tid] + red[1][tid] + red[2][tid] + red[3][tid];
        float m = sc;
        #pragma unroll
        for (int off = 32; off; off >>= 1) m = fmaxf(m, __shfl_xor(m, off));
        float e = expf(sc - m);
        float ss = e;
        #pragma unroll
        for (int off = 32; off; off >>= 1) ss += __shfl_xor(ss, off);
        out[k * NC + tid] = e / ss;
    }
}

extern "C" void kernel_launch(void* const* d_in, const int* in_sizes, int n_in,
                              void* d_out, int out_size, void* d_ws, size_t ws_size,
                              hipStream_t stream)
{
    const float* x  = (const float*)d_in[0];
    const float* W1 = (const float*)d_in[1];
    const float* b1 = (const float*)d_in[2];
    const float* W2 = (const float*)d_in[3];
    const float* b2 = (const float*)d_in[4];
    const float* W3 = (const float*)d_in[5];
    const float* b3 = (const float*)d_in[6];
    const float* W4 = (const float*)d_in[7];
    const float* b4 = (const float*)d_in[8];
    const float* Wc = (const float*)d_in[9];
    const float* bc = (const float*)d_in[10];
    float* out = (float*)d_out;

    float* ws     = (float*)d_ws;
    float* Dm     = ws;                       // 10000
    float* G      = ws + 10016;               // 16384 (fully overwritten)
    float* pooled = ws + 26400;               // 8192
    float* uu     = pooled + 8192;            // 16384
    float* oo     = uu + 16384;               // 8192
    unsigned short* W1h = (unsigned short*)(oo + 8192);
    unsigned short* W1l = W1h + 3 * D2Z * DZ;
    unsigned short* xh  = W1l + 3 * D2Z * DZ;
    unsigned short* xl  = xh + 400 * DZ;

    k_prep  <<<884,            256, 0, stream>>>(x, W1, W1h, W1l, xh, xl, Dm);
    k_fused <<<256,            256, 0, stream>>>(xh, xl, W1h, W1l, b1, Dm, G);
    k_pooled<<<dim3(8, NT),    256, 0, stream>>>(G, Dm, W2, b2, pooled);
    k_u     <<<dim3(16, NT),   256, 0, stream>>>(pooled, W3, b3, uu);
    k_o     <<<dim3(8, NT),    256, 0, stream>>>(uu, W4, b4, oo);
    k_score <<<NT,             256, 0, stream>>>(oo, Wc, bc, out);
}

// Round 10
// 151.519 us; speedup vs baseline: 4.8111x; 1.0127x over previous
//
#include <hip/hip_runtime.h>
#include <math.h>

#define NT 16
#define NR 25
#define DZ 512
#define D2Z 1024
#define NC 64

typedef short bf16x8 __attribute__((ext_vector_type(8)));
typedef float f32x4  __attribute__((ext_vector_type(4)));

#define TP  76    // convW LDS tile pitch (ushorts)
#define XSP 520   // x LDS pitch (ushorts): 1040B rows, 16B-aligned, bank-spread
#define XP2 136   // ws pitch for BK=128 (ushorts): 272B rows
#define CP  68    // C tile pitch (floats)

static __device__ inline unsigned short f2bf(float v) {
    union { float f; unsigned u; } x; x.f = v;
    unsigned r = x.u + 0x7fffu + ((x.u >> 16) & 1u);
    return (unsigned short)(r >> 16);
}
static __device__ inline float bf2f(unsigned short h) {
    union { float f; unsigned u; } x; x.u = ((unsigned)h) << 16; return x.f;
}

// ---------------------------------------------------------------------------
// k_prep: blocks 0..383 convW transpose+split (verified body); 384..783
// pairwise distances (verified body). convX eliminated (inline in k_fused).
// ---------------------------------------------------------------------------
__global__ __launch_bounds__(256) void k_prep(
    const float* __restrict__ x, const float* __restrict__ W1,
    unsigned short* __restrict__ W1h, unsigned short* __restrict__ W1l,
    float* __restrict__ Dm)
{
    __shared__ unsigned short th[64 * TP], tl[64 * TP];
    int vb = blockIdx.x;
    int tid = threadIdx.x;

    if (vb < 384) {
        int r0 = (vb % 24) * 64;
        int j0 = (vb / 24) * 64;
        int c  = r0 >> 9;
        int rb = r0 & 511;

        #pragma unroll
        for (int it = 0; it < 4; it++) {
            int rl = (tid >> 4) + it * 16;
            int jj = (tid & 15) * 4;
            float4 v = *(const float4*)(W1 + (size_t)(r0 + rl) * D2Z + j0 + jj);
            unsigned short h0 = f2bf(v.x), h1 = f2bf(v.y), h2 = f2bf(v.z), h3 = f2bf(v.w);
            th[rl * TP + jj + 0] = h0; tl[rl * TP + jj + 0] = f2bf(v.x - bf2f(h0));
            th[rl * TP + jj + 1] = h1; tl[rl * TP + jj + 1] = f2bf(v.y - bf2f(h1));
            th[rl * TP + jj + 2] = h2; tl[rl * TP + jj + 2] = f2bf(v.z - bf2f(h2));
            th[rl * TP + jj + 3] = h3; tl[rl * TP + jj + 3] = f2bf(v.w - bf2f(h3));
        }
        __syncthreads();

        #pragma unroll
        for (int it = 0; it < 4; it++) {
            int jl = (tid >> 4) + it * 16;
            int r4 = (tid & 15) * 4;
            ushort4 hv = make_ushort4(th[(r4+0)*TP + jl], th[(r4+1)*TP + jl],
                                      th[(r4+2)*TP + jl], th[(r4+3)*TP + jl]);
            ushort4 lv = make_ushort4(tl[(r4+0)*TP + jl], tl[(r4+1)*TP + jl],
                                      tl[(r4+2)*TP + jl], tl[(r4+3)*TP + jl]);
            size_t dst = ((size_t)c * D2Z + j0 + jl) * DZ + rb + r4;
            *(ushort4*)(W1h + dst) = hv;
            *(ushort4*)(W1l + dst) = lv;
        }
    } else {
        int i = vb - 384;
        int k = i & 15, a = i >> 4;
        int lane = tid & 63;
        int w    = tid >> 6;
        const float* xk = x + (size_t)k * NR * DZ;

        const float4* xap = (const float4*)(xk + a * DZ);
        float4 a0 = xap[lane];
        float4 a1 = xap[lane + 64];

        float sa = a0.x*a0.x + a0.y*a0.y + a0.z*a0.z + a0.w*a0.w
                 + a1.x*a1.x + a1.y*a1.y + a1.z*a1.z + a1.w*a1.w;
        #pragma unroll
        for (int off = 32; off; off >>= 1) sa += __shfl_xor(sa, off);
        float inva = 1.0f / sqrtf(sa);
        a0.x *= inva; a0.y *= inva; a0.z *= inva; a0.w *= inva;
        a1.x *= inva; a1.y *= inva; a1.z *= inva; a1.w *= inva;
        float sqa = a0.x*a0.x + a0.y*a0.y + a0.z*a0.z + a0.w*a0.w
                  + a1.x*a1.x + a1.y*a1.y + a1.z*a1.z + a1.w*a1.w;
        #pragma unroll
        for (int off = 32; off; off >>= 1) sqa += __shfl_xor(sqa, off);

        for (int j = w; j < NR; j += 4) {
            const float4* xjp = (const float4*)(xk + j * DZ);
            float4 j0 = xjp[lane];
            float4 j1 = xjp[lane + 64];
            float sj = j0.x*j0.x + j0.y*j0.y + j0.z*j0.z + j0.w*j0.w
                     + j1.x*j1.x + j1.y*j1.y + j1.z*j1.z + j1.w*j1.w;
            #pragma unroll
            for (int off = 32; off; off >>= 1) sj += __shfl_xor(sj, off);
            float invj = 1.0f / sqrtf(sj);
            j0.x *= invj; j0.y *= invj; j0.z *= invj; j0.w *= invj;
            j1.x *= invj; j1.y *= invj; j1.z *= invj; j1.w *= invj;

            float sqj = j0.x*j0.x + j0.y*j0.y + j0.z*j0.z + j0.w*j0.w
                      + j1.x*j1.x + j1.y*j1.y + j1.z*j1.z + j1.w*j1.w;
            float dij = a0.x*j0.x + a0.y*j0.y + a0.z*j0.z + a0.w*j0.w
                      + a1.x*j1.x + a1.y*j1.y + a1.z*j1.z + a1.w*j1.w;
            #pragma unroll
            for (int off = 32; off; off >>= 1) {
                sqj += __shfl_xor(sqj, off);
                dij += __shfl_xor(dij, off);
            }
            float d2 = sqa + sqj - 2.0f * dij;
            float d  = sqrtf(fmaxf(d2, 0.0f));
            if (lane == 0) Dm[((size_t)k * NR + a) * NR + j] = d;
        }
    }
}

// ---------------------------------------------------------------------------
// k_fused v3: per (task k, 64-col j-tile) GEMM+accum.
//  - x staged ONCE from fp32 (inline f2bf split -> bit-identical to convX),
//    26 LDS rows (row 25 zeroed; pad lanes m>=25 read it).
//  - per (c,kk) barriers carry only W staging (reads precomputed W1h/W1l).
//  - XCD swizzle bid = k*16+jt; BK=128; MFMA k-order identical to R9.
// LDS ~116 KB -> 1 block/CU (R9's 82 KB compiled+ran; limit 160).
// ---------------------------------------------------------------------------
__global__ __launch_bounds__(256) void k_fused(
    const float* __restrict__ x,
    const unsigned short* __restrict__ W1h, const unsigned short* __restrict__ W1l,
    const float* __restrict__ b1, const float* __restrict__ Dm,
    float* __restrict__ G)
{
    __shared__ unsigned short xs_h[26 * XSP], xs_l[26 * XSP];   // 26.4 KB each
    __shared__ unsigned short ws_h[64 * XP2], ws_l[64 * XP2];   // 17 KB each
    __shared__ float Ct[96 * CP];                               // 26.1 KB
    __shared__ float Dm_s[NR * NR];
    __shared__ float red[4][64];

    int bid = blockIdx.x;
    int k  = bid >> 4;          // task
    int jt = bid & 15;          // j-tile -> XCD = jt % 8 for all k
    int j0 = jt * 64;

    int tid  = threadIdx.x;
    int lane = tid & 63;
    int w    = tid >> 6;
    int q    = lane >> 4;
    int ln16 = lane & 15;

    for (int idx = tid; idx < NR * NR; idx += 256)
        Dm_s[idx] = Dm[(size_t)k * NR * NR + idx];

    // ---- stage x once: rows 0..24 converted inline, row 25 zeroed ----
    for (int g = tid; g < NR * 64; g += 256) {
        int row = g >> 6;
        int c8  = (g & 63) * 8;
        const float* xp = x + ((size_t)k * NR + row) * DZ + c8;
        float4 v0 = *(const float4*)(xp);
        float4 v1 = *(const float4*)(xp + 4);
        unsigned short h;
        ushort4 ha, hb, la, lb;
        h = f2bf(v0.x); ha.x = h; la.x = f2bf(v0.x - bf2f(h));
        h = f2bf(v0.y); ha.y = h; la.y = f2bf(v0.y - bf2f(h));
        h = f2bf(v0.z); ha.z = h; la.z = f2bf(v0.z - bf2f(h));
        h = f2bf(v0.w); ha.w = h; la.w = f2bf(v0.w - bf2f(h));
        h = f2bf(v1.x); hb.x = h; lb.x = f2bf(v1.x - bf2f(h));
        h = f2bf(v1.y); hb.y = h; lb.y = f2bf(v1.y - bf2f(h));
        h = f2bf(v1.z); hb.z = h; lb.z = f2bf(v1.z - bf2f(h));
        h = f2bf(v1.w); hb.w = h; lb.w = f2bf(v1.w - bf2f(h));
        *(ushort4*)&xs_h[row * XSP + c8]     = ha;
        *(ushort4*)&xs_h[row * XSP + c8 + 4] = hb;
        *(ushort4*)&xs_l[row * XSP + c8]     = la;
        *(ushort4*)&xs_l[row * XSP + c8 + 4] = lb;
    }
    for (int g = tid; g < DZ; g += 256) {
        xs_h[25 * XSP + g] = 0;
        xs_l[25 * XSP + g] = 0;
    }

    int rowA1 = 16 + ln16;
    if (rowA1 > 25) rowA1 = 25;    // pad rows read the zero row

    for (int c = 0; c < 3; c++) {
        f32x4 acc0 = (f32x4){0.f,0.f,0.f,0.f};
        f32x4 acc1 = (f32x4){0.f,0.f,0.f,0.f};

        for (int kk = 0; kk < 4; kk++) {
            int kbase = kk * 128;
            // stage W chunk: 64 n-rows x 128 k
            #pragma unroll
            for (int it = 0; it < 4; it++) {
                int g   = tid + 256 * it;      // 0..1023
                int row = g >> 4;              // 0..63
                int kg  = (g & 15) * 8;
                size_t off = ((size_t)(c << 10) + j0 + row) * DZ + kbase + kg;
                *(uint4*)&ws_h[row * XP2 + kg] = *(const uint4*)(W1h + off);
                *(uint4*)&ws_l[row * XP2 + kg] = *(const uint4*)(W1l + off);
            }
            __syncthreads();   // also covers xs/Dm_s staging on first pass

            #pragma unroll
            for (int ks = 0; ks < 4; ks++) {
                int ko  = ks * 32 + q * 8;          // within chunk (ws)
                int kog = kbase + ko;               // global k (xs)
                bf16x8 b_h = *(const bf16x8*)&ws_h[(w * 16 + ln16) * XP2 + ko];
                bf16x8 b_l = *(const bf16x8*)&ws_l[(w * 16 + ln16) * XP2 + ko];
                {
                    bf16x8 a_h = *(const bf16x8*)&xs_h[ln16 * XSP + kog];
                    bf16x8 a_l = *(const bf16x8*)&xs_l[ln16 * XSP + kog];
                    acc0 = __builtin_amdgcn_mfma_f32_16x16x32_bf16(a_h, b_h, acc0, 0, 0, 0);
                    acc0 = __builtin_amdgcn_mfma_f32_16x16x32_bf16(a_h, b_l, acc0, 0, 0, 0);
                    acc0 = __builtin_amdgcn_mfma_f32_16x16x32_bf16(a_l, b_h, acc0, 0, 0, 0);
                }
                {
                    bf16x8 a_h = *(const bf16x8*)&xs_h[rowA1 * XSP + kog];
                    bf16x8 a_l = *(const bf16x8*)&xs_l[rowA1 * XSP + kog];
                    acc1 = __builtin_amdgcn_mfma_f32_16x16x32_bf16(a_h, b_h, acc1, 0, 0, 0);
                    acc1 = __builtin_amdgcn_mfma_f32_16x16x32_bf16(a_h, b_l, acc1, 0, 0, 0);
                    acc1 = __builtin_amdgcn_mfma_f32_16x16x32_bf16(a_l, b_h, acc1, 0, 0, 0);
                }
            }
            __syncthreads();
        }

        int col = w * 16 + ln16;
        #pragma unroll
        for (int r = 0; r < 4; r++) {
            Ct[(c * 32 + q * 4 + r) * CP + col]      = acc0[r];
            Ct[(c * 32 + 16 + q * 4 + r) * CP + col] = acc1[r];
        }
    }
    __syncthreads();

    // ---- in-block accum: thread = (column j, valid-m index h) ----
    int j = tid & 63;
    int h = tid >> 6;
    float b1v = b1[j0 + j];

    float a2v[NR], a3v[NR];
    #pragma unroll
    for (int i = 0; i < NR; i++) a2v[i] = Ct[(32 + i) * CP + j];
    #pragma unroll
    for (int i = 0; i < NR; i++) a3v[i] = Ct[(64 + i) * CP + j];

    float acc = 0.0f;
    #pragma unroll
    for (int a = 0; a < NR; a++) {
        const int qa = a % 5, mdiv = a / 5;
        int m = h + (h >= mdiv);
        int p = qa + 5 * m;
        float a1  = Ct[a * CP + j];
        float dap = Dm_s[a * NR + p];
        float s = a1 + a2v[p] + b1v;
        #pragma unroll
        for (int ng = 0; ng < 5; ng++) {
            #pragma unroll
            for (int o = 0; o < 4; o++) {
                int n = ng * 5 + o + (o >= qa);
                float tm = Dm_s[a * NR + n] - dap;
                bool sel = (tm > 0.0f) && (tm <= 0.8f);
                float pre = fmaxf(s + a3v[n], 0.0f);
                float msk = sel ? 1.0f : 0.0f;
                acc = fmaf(msk, pre, acc);
            }
        }
    }
    red[h][j] = acc;
    __syncthreads();
    if (tid < 64)
        G[(size_t)k * D2Z + j0 + tid] = red[0][tid] + red[1][tid]
                                      + red[2][tid] + red[3][tid];
}

// ---------------------------------------------------------------------------
// Tail (verified R9 bodies: 4 independent accumulators, local cnt).
// ---------------------------------------------------------------------------
__global__ __launch_bounds__(256) void k_pooled(const float* __restrict__ G,
                                                const float* __restrict__ Dm,
                                                const float* __restrict__ W2,
                                                const float* __restrict__ b2,
                                                float* __restrict__ pooled)
{
    int bx = blockIdx.x, k = blockIdx.y;
    int tid = threadIdx.x, lane = tid & 63, kc = tid >> 6;
    int col = bx * 64 + lane;

    const float* Dk = Dm + (size_t)k * NR * NR;
    float cntv = 0.0f;
    for (int idx = tid; idx < 2000; idx += 256) {
        int a   = idx / 80;
        int rem = idx - a * 80;
        int mi  = rem / 20;
        int nn  = rem - mi * 20;
        int qa = a % 5, mdiv = a / 5;
        int m = mi + (mi >= mdiv);
        int p = qa + 5 * m;
        int ng = nn >> 2, o = nn & 3;
        int n = ng * 5 + o + (o >= qa);
        float tm = Dk[a * NR + n] - Dk[a * NR + p];
        cntv += ((tm > 0.0f) && (tm <= 0.8f)) ? 1.0f : 0.0f;
    }
    #pragma unroll
    for (int off = 32; off; off >>= 1) cntv += __shfl_xor(cntv, off);

    __shared__ float red[4][64];
    __shared__ float cred[4];
    if (lane == 0) cred[kc] = cntv;

    const float* Gk = G + (size_t)k * D2Z;
    float a0 = 0.f, a1 = 0.f, a2 = 0.f, a3 = 0.f;
    int j0 = kc * 256;
    #pragma unroll 4
    for (int jj = j0; jj < j0 + 256; jj += 4) {
        a0 = fmaf(Gk[jj+0], W2[(size_t)(jj+0) * DZ + col], a0);
        a1 = fmaf(Gk[jj+1], W2[(size_t)(jj+1) * DZ + col], a1);
        a2 = fmaf(Gk[jj+2], W2[(size_t)(jj+2) * DZ + col], a2);
        a3 = fmaf(Gk[jj+3], W2[(size_t)(jj+3) * DZ + col], a3);
    }
    red[kc][lane] = (a0 + a1) + (a2 + a3);
    __syncthreads();
    if (tid < 64) {
        float cnt = cred[0] + cred[1] + cred[2] + cred[3];
        float s = red[0][lane] + red[1][lane] + red[2][lane] + red[3][lane];
        s += cnt * b2[col];
        pooled[(size_t)k * DZ + col] = s;
    }
}

__global__ __launch_bounds__(256) void k_u(const float* __restrict__ pooled,
                                           const float* __restrict__ W3,
                                           const float* __restrict__ b3,
                                           float* __restrict__ u)
{
    int bx = blockIdx.x, k = blockIdx.y;
    int tid = threadIdx.x, lane = tid & 63, kc = tid >> 6;
    int col = bx * 64 + lane;

    const float* Pk = pooled + (size_t)k * DZ;
    float a0 = 0.f, a1 = 0.f, a2 = 0.f, a3 = 0.f;
    int s0 = kc * 128;
    #pragma unroll 4
    for (int s = s0; s < s0 + 128; s += 4) {
        a0 = fmaf(Pk[s+0], W3[(size_t)(s+0) * D2Z + col], a0);
        a1 = fmaf(Pk[s+1], W3[(size_t)(s+1) * D2Z + col], a1);
        a2 = fmaf(Pk[s+2], W3[(size_t)(s+2) * D2Z + col], a2);
        a3 = fmaf(Pk[s+3], W3[(size_t)(s+3) * D2Z + col], a3);
    }
    __shared__ float red[4][64];
    red[kc][lane] = (a0 + a1) + (a2 + a3);
    __syncthreads();
    if (tid < 64) {
        float v = red[0][lane] + red[1][lane] + red[2][lane] + red[3][lane] + b3[col];
        u[(size_t)k * D2Z + col] = fmaxf(v, 0.0f);
    }
}

__global__ __launch_bounds__(256) void k_o(const float* __restrict__ u,
                                           const float* __restrict__ W4,
                                           const float* __restrict__ b4,
                                           float* __restrict__ o)
{
    int bx = blockIdx.x, k = blockIdx.y;
    int tid = threadIdx.x, lane = tid & 63, kc = tid >> 6;
    int col = bx * 64 + lane;

    const float* Uk = u + (size_t)k * D2Z;
    float a0 = 0.f, a1 = 0.f, a2 = 0.f, a3 = 0.f;
    int j0 = kc * 256;
    #pragma unroll 4
    for (int jj = j0; jj < j0 + 256; jj += 4) {
        a0 = fmaf(Uk[jj+0], W4[(size_t)(jj+0) * DZ + col], a0);
        a1 = fmaf(Uk[jj+1], W4[(size_t)(jj+1) * DZ + col], a1);
        a2 = fmaf(Uk[jj+2], W4[(size_t)(jj+2) * DZ + col], a2);
        a3 = fmaf(Uk[jj+3], W4[(size_t)(jj+3) * DZ + col], a3);
    }
    __shared__ float red[4][64];
    red[kc][lane] = (a0 + a1) + (a2 + a3);
    __syncthreads();
    if (tid < 64) {
        o[(size_t)k * DZ + col] = red[0][lane] + red[1][lane] + red[2][lane]
                                + red[3][lane] + b4[col];
    }
}

__global__ __launch_bounds__(256) void k_score(const float* __restrict__ o,
                                               const float* __restrict__ Wc,
                                               const float* __restrict__ bc,
                                               float* __restrict__ out)
{
    int k = blockIdx.x;
    int tid = threadIdx.x, oc = tid & 63, kc = tid >> 6;

    const float* Ok = o + (size_t)k * DZ;
    float a0 = 0.f, a1 = 0.f, a2 = 0.f, a3 = 0.f;
    int r0 = kc * 128;
    #pragma unroll 4
    for (int rr = r0; rr < r0 + 128; rr += 4) {
        a0 = fmaf(Ok[rr+0], Wc[(size_t)(rr+0) * NC + oc], a0);
        a1 = fmaf(Ok[rr+1], Wc[(size_t)(rr+1) * NC + oc], a1);
        a2 = fmaf(Ok[rr+2], Wc[(size_t)(rr+2) * NC + oc], a2);
        a3 = fmaf(Ok[rr+3], Wc[(size_t)(rr+3) * NC + oc], a3);
    }
    __shared__ float red[4][64];
    red[kc][oc] = (a0 + a1) + (a2 + a3);
    __syncthreads();
    if (tid < 64) {
        float sc = bc[tid] + red[0][tid] + red[1][tid] + red[2][tid] + red[3][tid];
        float m = sc;
        #pragma unroll
        for (int off = 32; off; off >>= 1) m = fmaxf(m, __shfl_xor(m, off));
        float e = expf(sc - m);
        float ss = e;
        #pragma unroll
        for (int off = 32; off; off >>= 1) ss += __shfl_xor(ss, off);
        out[k * NC + tid] = e / ss;
    }
}

extern "C" void kernel_launch(void* const* d_in, const int* in_sizes, int n_in,
                              void* d_out, int out_size, void* d_ws, size_t ws_size,
                              hipStream_t stream)
{
    const float* x  = (const float*)d_in[0];
    const float* W1 = (const float*)d_in[1];
    const float* b1 = (const float*)d_in[2];
    const float* W2 = (const float*)d_in[3];
    const float* b2 = (const float*)d_in[4];
    const float* W3 = (const float*)d_in[5];
    const float* b3 = (const float*)d_in[6];
    const float* W4 = (const float*)d_in[7];
    const float* b4 = (const float*)d_in[8];
    const float* Wc = (const float*)d_in[9];
    const float* bc = (const float*)d_in[10];
    float* out = (float*)d_out;

    float* ws     = (float*)d_ws;
    float* Dm     = ws;                       // 10000
    float* G      = ws + 10016;               // 16384 (fully overwritten)
    float* pooled = ws + 26400;               // 8192
    float* uu     = pooled + 8192;            // 16384
    float* oo     = uu + 16384;               // 8192
    unsigned short* W1h = (unsigned short*)(oo + 8192);
    unsigned short* W1l = W1h + 3 * D2Z * DZ;

    k_prep  <<<784,            256, 0, stream>>>(x, W1, W1h, W1l, Dm);
    k_fused <<<256,            256, 0, stream>>>(x, W1h, W1l, b1, Dm, G);
    k_pooled<<<dim3(8, NT),    256, 0, stream>>>(G, Dm, W2, b2, pooled);
    k_u     <<<dim3(16, NT),   256, 0, stream>>>(pooled, W3, b3, uu);
    k_o     <<<dim3(8, NT),    256, 0, stream>>>(uu, W4, b4, oo);
    k_score <<<NT,             256, 0, stream>>>(oo, Wc, bc, out);
}